// Round 1
// baseline (2926.974 us; speedup 1.0000x reference)
//
#include <hip/hip_runtime.h>
#include <math.h>

// Problem constants (fixed by the reference setup_inputs).
constexpr int N_NODES = 50000;
constexpr int IN_F    = 512;
constexpr int H_F     = 256;
constexpr int OUT_F   = 512;
constexpr int N_EDGE  = 800000;
constexpr int NDIM    = 4;
constexpr long NH     = (long)N_NODES * H_F;   // 12,800,000

#define LEAKY_SLOPE 0.01f

__device__ __forceinline__ float leaky_f(float v) { return v > 0.0f ? v : LEAKY_SLOPE * v; }

typedef __bf16 bf16x8 __attribute__((ext_vector_type(8)));
typedef float  f32x4  __attribute__((ext_vector_type(4)));

// async global->LDS, 16B per lane. LDS dest is wave-uniform base + lane*16
// (our per-lane addresses satisfy this by construction).
__device__ __forceinline__ void gload16(const void* g, void* s) {
  __builtin_amdgcn_global_load_lds(
      (const __attribute__((address_space(1))) void*)g,
      (__attribute__((address_space(3))) void*)s, 16, 0, 0);
}

// ---------------------------------------------------------------------------
// Split-bf16 MFMA GEMM: out = maybe_leaky(maybe_C + bias + A @ B)
// All bf16 operands pre-split hi/lo in global; staged via global_load_lds into
// linear [128][32] LDS (64B row stride -> conflict-free ds_read_b128).
// 128x128 tile, 4 waves (2x2), 4x4 of 16x16x32 MFMA, 3 MFMA/product (hh+hl+lh).
// AF32=true: A is fp32, split on the fly through VALU (used for attention GEMM
// and as a fallback for G1 when the workspace can't hold a split copy of x).
// A is 2-chunked (A1 for k<kSplit else A2) for the fused [WB|R] GEMM.
// Epilogue: optional bias vector, optional fp32 accumulate, optional leaky,
// and either fp32 store (C) or split-bf16 store (Oh/Ol).
// grid = (N/128, ceil(M/128)): adjacent blocks share the A row-panel (L2/L3).
// ---------------------------------------------------------------------------
template<bool AF32>
__global__ __launch_bounds__(256) void gemm_k(
    const float* __restrict__ Af, int ldaf,
    const __bf16* __restrict__ A1h, const __bf16* __restrict__ A1l, int lda1,
    const __bf16* __restrict__ A2h, const __bf16* __restrict__ A2l, int lda2, int kSplit,
    const __bf16* __restrict__ BhT, const __bf16* __restrict__ BlT,
    float* __restrict__ C, int ldc,
    const float* __restrict__ biasVec,
    __bf16* __restrict__ Oh, __bf16* __restrict__ Ol, int ldo,
    int M, int N, int K, int accumulate, int leaky)
{
  __shared__ __bf16 Ash[128][32];
  __shared__ __bf16 Asl[128][32];
  __shared__ __bf16 Bsh[128][32];
  __shared__ __bf16 Bsl[128][32];

  const int tid  = threadIdx.x;
  const int lane = tid & 63;
  const int wid  = tid >> 6;
  const int wm   = wid & 1;
  const int wn   = wid >> 1;
  const int l15  = lane & 15;
  const int quad = lane >> 4;
  const int col0 = blockIdx.x * 128;
  const int row0 = blockIdx.y * 128;

  f32x4 acc[4][4] = {};
  const int nkt = K >> 5;

  for (int kt = 0; kt < nkt; ++kt) {
    const int kk = kt << 5;
    __syncthreads();   // previous iteration's ds_reads are done (lgkm waited before MFMA)

    if constexpr (AF32) {
      // A via VALU split (fp32 source)
      #pragma unroll
      for (int p = 0; p < 4; ++p) {
        const int m = (tid >> 3) + p * 32;
        int row = row0 + m; row = row < M ? row : M - 1;
        const float4 v = *(const float4*)(Af + (size_t)row * ldaf + kk + (tid & 7) * 4);
        const float f[4] = {v.x, v.y, v.z, v.w};
        union { __bf16 b[4]; short4 s; } hh, ll;
        #pragma unroll
        for (int i = 0; i < 4; ++i) {
          const __bf16 hb = (__bf16)f[i];
          hh.b[i] = hb;
          ll.b[i] = (__bf16)(f[i] - (float)hb);
        }
        *(short4*)&Ash[m][(tid & 7) * 4] = hh.s;
        *(short4*)&Asl[m][(tid & 7) * 4] = ll.s;
      }
    } else {
      // A via DMA (pre-split bf16), chunked at kSplit
      const __bf16* Ah; const __bf16* Al; int lda, k0;
      if (kk < kSplit) { Ah = A1h; Al = A1l; lda = lda1; k0 = kk; }
      else             { Ah = A2h; Al = A2l; lda = lda2; k0 = kk - kSplit; }
      #pragma unroll
      for (int p = 0; p < 2; ++p) {
        const int c = tid + p * 256;           // chunk id: row=c>>2, 16B col chunk=c&3
        int row = row0 + (c >> 2); row = row < M ? row : M - 1;
        const size_t go = (size_t)row * lda + k0 + (c & 3) * 8;
        gload16(Ah + go, (__bf16*)Ash + (size_t)c * 8);
        gload16(Al + go, (__bf16*)Asl + (size_t)c * 8);
      }
    }
    // B via DMA (pre-split bf16, B^T layout [N][K], ldb == K)
    #pragma unroll
    for (int p = 0; p < 2; ++p) {
      const int c = tid + p * 256;
      const int nn = col0 + (c >> 2);
      const size_t go = (size_t)nn * K + kk + (c & 3) * 8;
      gload16(BhT + go, (__bf16*)Bsh + (size_t)c * 8);
      gload16(BlT + go, (__bf16*)Bsl + (size_t)c * 8);
    }
    __syncthreads();   // compiler drains vmcnt(0): all DMA landed in LDS

    bf16x8 ah[4], al[4], bh[4], bl[4];
    #pragma unroll
    for (int t = 0; t < 4; ++t) {
      ah[t] = *(const bf16x8*)&Ash[wm * 64 + t * 16 + l15][quad * 8];
      al[t] = *(const bf16x8*)&Asl[wm * 64 + t * 16 + l15][quad * 8];
      bh[t] = *(const bf16x8*)&Bsh[wn * 64 + t * 16 + l15][quad * 8];
      bl[t] = *(const bf16x8*)&Bsl[wn * 64 + t * 16 + l15][quad * 8];
    }
    #pragma unroll
    for (int mt = 0; mt < 4; ++mt)
      #pragma unroll
      for (int nt = 0; nt < 4; ++nt) {
        acc[mt][nt] = __builtin_amdgcn_mfma_f32_16x16x32_bf16(ah[mt], bh[nt], acc[mt][nt], 0, 0, 0);
        acc[mt][nt] = __builtin_amdgcn_mfma_f32_16x16x32_bf16(ah[mt], bl[nt], acc[mt][nt], 0, 0, 0);
        acc[mt][nt] = __builtin_amdgcn_mfma_f32_16x16x32_bf16(al[mt], bh[nt], acc[mt][nt], 0, 0, 0);
      }
  }

  // Epilogue: C/D layout col=lane&15, row=quad*4+reg
  #pragma unroll
  for (int mt = 0; mt < 4; ++mt)
    #pragma unroll
    for (int nt = 0; nt < 4; ++nt) {
      const int col = col0 + wn * 64 + nt * 16 + l15;
      const float bv = biasVec ? biasVec[col] : 0.0f;
      #pragma unroll
      for (int r = 0; r < 4; ++r) {
        const int row = row0 + wm * 64 + mt * 16 + quad * 4 + r;
        if (row < M) {
          float v = acc[mt][nt][r] + bv;
          if (accumulate) v += C[(size_t)row * ldc + col];
          if (leaky) v = leaky_f(v);
          if (Oh) {
            const __bf16 hv = (__bf16)v;
            Oh[(size_t)row * ldo + col] = hv;
            Ol[(size_t)row * ldo + col] = (__bf16)(v - (float)hv);
          } else {
            C[(size_t)row * ldc + col] = v;
          }
        }
      }
    }
}

// ---------------------------------------------------------------------------
// Weight prep: transpose + hi/lo split.  B:[Z][Kd][Nd] -> out:[Z][Nd][Kd]
// ---------------------------------------------------------------------------
__global__ void splitT_kernel(const float* __restrict__ B, __bf16* __restrict__ h,
                              __bf16* __restrict__ l, int Kd, int Nd, int total)
{
  int i = blockIdx.x * 256 + threadIdx.x;
  if (i >= total) return;
  int z   = i / (Kd * Nd);
  int rem = i - z * (Kd * Nd);
  int k = rem / Nd;
  int n = rem - k * Nd;
  float v = B[i];
  __bf16 hv = (__bf16)v;
  long o = (long)z * Kd * Nd + (long)n * Kd + k;
  h[o] = hv;
  l[o] = (__bf16)(v - (float)hv);
}

// Non-transposing split (for x -> xh/xl)
__global__ void splitA_kernel(const float* __restrict__ A, __bf16* __restrict__ h,
                              __bf16* __restrict__ l, long total)
{
  long i = (long)blockIdx.x * 256 + threadIdx.x;
  if (i >= total) return;
  float v = A[i];
  __bf16 hv = (__bf16)v;
  h[i] = hv;
  l[i] = (__bf16)(v - (float)hv);
}

// BcatT[d][n][k] (k<H: invW[d*H+k][n]; else 0.5*sum_b att[d*4+b]*invW[b*H+(k-H)][n])
__global__ void bcat_kernel(const float* __restrict__ invW, const float* __restrict__ att,
                            __bf16* __restrict__ h, __bf16* __restrict__ l)
{
  int i = blockIdx.x * 256 + threadIdx.x;           // over 4*512*512
  if (i >= NDIM * OUT_F * 512) return;
  int d   = i >> 18;
  int rem = i & 262143;
  int n = rem >> 9;
  int k = rem & 511;
  float v;
  if (k < H_F) {
    v = invW[(long)(d * H_F + k) * OUT_F + n];
  } else {
    float s = 0.f;
    #pragma unroll
    for (int b = 0; b < 4; ++b)
      s += att[d * 4 + b] * invW[(long)(b * H_F + (k - H_F)) * OUT_F + n];
    v = 0.5f * s;
  }
  __bf16 hv = (__bf16)v;
  h[i] = hv;
  l[i] = (__bf16)(v - (float)hv);
}

// ---------------------------------------------------------------------------
// CSR build: count in-degrees, scan to row offsets, fill src buckets.
// ---------------------------------------------------------------------------
__global__ void deg_count_kernel(const int* __restrict__ edges, int* __restrict__ cnt, int E)
{
  int i = blockIdx.x * 256 + threadIdx.x;
  if (i >= NDIM * E) return;
  int d = i / E;
  int e = i - d * E;
  int t = edges[(long)d * 2 * E + E + e];
  atomicAdd(&cnt[d * N_NODES + t], 1);
}

__global__ __launch_bounds__(1024) void scan_kernel(const int* __restrict__ cnt,
                                                    int* __restrict__ row_start,
                                                    float* __restrict__ dinv)
{
  const int d    = blockIdx.x;
  const int tid  = threadIdx.x;
  const int lane = tid & 63;
  const int wid  = tid >> 6;
  __shared__ int wsum[16];
  __shared__ int carry_s;
  if (tid == 0) carry_s = 0;
  __syncthreads();
  for (int base = 0; base < N_NODES; base += 1024) {
    int i = base + tid;
    int v = (i < N_NODES) ? cnt[d * N_NODES + i] : 0;
    if (i < N_NODES) dinv[d * N_NODES + i] = sqrtf(0.5f / (float)(v + 1));
    int incl = v;
    #pragma unroll
    for (int off = 1; off < 64; off <<= 1) {
      int nb = __shfl_up(incl, off, 64);
      if (lane >= off) incl += nb;
    }
    if (lane == 63) wsum[wid] = incl;
    __syncthreads();
    if (wid == 0 && lane < 16) {
      int s = wsum[lane];
      #pragma unroll
      for (int off = 1; off < 16; off <<= 1) {
        int nb = __shfl_up(s, off, 16);
        if (lane >= off) s += nb;
      }
      wsum[lane] = s;
    }
    __syncthreads();
    int waveoff = (wid == 0) ? 0 : wsum[wid - 1];
    if (i < N_NODES) row_start[d * (N_NODES + 1) + i] = carry_s + waveoff + incl - v;
    __syncthreads();
    if (tid == 1023) carry_s += wsum[15];
    __syncthreads();
  }
  if (tid == 0) row_start[d * (N_NODES + 1) + N_NODES] = carry_s;
}

__global__ void fill_kernel(const int* __restrict__ edges, const int* __restrict__ row_start,
                            int* __restrict__ fill_cnt, int* __restrict__ csr_src, int E)
{
  int i = blockIdx.x * 256 + threadIdx.x;
  if (i >= NDIM * E) return;
  int d = i / E;
  int e = i - d * E;
  int s = edges[(long)d * 2 * E + e];
  int t = edges[(long)d * 2 * E + E + e];
  int pos = row_start[d * (N_NODES + 1) + t] + atomicAdd(&fill_cnt[d * N_NODES + t], 1);
  csr_src[(long)d * E + pos] = s;
}

// ---------------------------------------------------------------------------
// Gather aggregation: one wave per dst node (no atomics), 2-edge unroll for
// MLP on the random (L3-resident) row reads; emits WB directly split bf16.
// ---------------------------------------------------------------------------
__global__ __launch_bounds__(256) void gather_aggr_kernel(
    const float* __restrict__ hw, const int* __restrict__ csr_src,
    const int* __restrict__ row_start, const float* __restrict__ dinv,
    const float* __restrict__ bias, __bf16* __restrict__ Wh, __bf16* __restrict__ Wl)
{
  const int n = blockIdx.x * 4 + (threadIdx.x >> 6);
  const int lane = threadIdx.x & 63;
  const float dt = dinv[n];
  const float sl = dt * dt;
  const float4 b = *(const float4*)(bias + lane * 4);
  const float4 h = *(const float4*)(hw + (size_t)n * H_F + lane * 4);
  float4 a0 = make_float4(0.5f * b.x + sl * h.x, 0.5f * b.y + sl * h.y,
                          0.5f * b.z + sl * h.z, 0.5f * b.w + sl * h.w);
  float4 a1 = make_float4(0.f, 0.f, 0.f, 0.f);
  const int beg = row_start[n];
  const int end = row_start[n + 1];
  int j = beg;
  for (; j + 2 <= end; j += 2) {
    const int s0 = csr_src[j];
    const int s1 = csr_src[j + 1];
    const float nm0 = dt * dinv[s0];
    const float nm1 = dt * dinv[s1];
    const float4 v0 = *(const float4*)(hw + (size_t)s0 * H_F + lane * 4);
    const float4 v1 = *(const float4*)(hw + (size_t)s1 * H_F + lane * 4);
    a0.x = fmaf(nm0, v0.x, a0.x); a0.y = fmaf(nm0, v0.y, a0.y);
    a0.z = fmaf(nm0, v0.z, a0.z); a0.w = fmaf(nm0, v0.w, a0.w);
    a1.x = fmaf(nm1, v1.x, a1.x); a1.y = fmaf(nm1, v1.y, a1.y);
    a1.z = fmaf(nm1, v1.z, a1.z); a1.w = fmaf(nm1, v1.w, a1.w);
  }
  if (j < end) {
    const int s0 = csr_src[j];
    const float nm0 = dt * dinv[s0];
    const float4 v0 = *(const float4*)(hw + (size_t)s0 * H_F + lane * 4);
    a0.x = fmaf(nm0, v0.x, a0.x); a0.y = fmaf(nm0, v0.y, a0.y);
    a0.z = fmaf(nm0, v0.z, a0.z); a0.w = fmaf(nm0, v0.w, a0.w);
  }
  const float av[4] = {a0.x + a1.x, a0.y + a1.y, a0.z + a1.z, a0.w + a1.w};
  union { __bf16 b[4]; short4 s; } H, L;
  #pragma unroll
  for (int i = 0; i < 4; ++i) {
    const __bf16 hv = (__bf16)av[i];
    H.b[i] = hv;
    L.b[i] = (__bf16)(av[i] - (float)hv);
  }
  *(short4*)(Wh + (size_t)n * H_F + lane * 4) = H.s;
  *(short4*)(Wl + (size_t)n * H_F + lane * 4) = L.s;
}

// ---------------------------------------------------------------------------
// Attention small kernels
// ---------------------------------------------------------------------------
__global__ void att_dot_kernel(const float* __restrict__ T, const float* __restrict__ P,
                               float* __restrict__ out16)
{
  const int a = blockIdx.x >> 2;
  const int b = blockIdx.x & 3;
  const float* ta = T + (long)a * (IN_F * H_F);
  const float* pb = P + (long)b * (IN_F * H_F);
  float s = 0.f;
  for (int i = threadIdx.x; i < IN_F * H_F; i += 256) s += ta[i] * pb[i];
  #pragma unroll
  for (int off = 32; off > 0; off >>= 1) s += __shfl_down(s, off, 64);
  __shared__ float red[4];
  if ((threadIdx.x & 63) == 0) red[threadIdx.x >> 6] = s;
  __syncthreads();
  if (threadIdx.x == 0) out16[blockIdx.x] = red[0] + red[1] + red[2] + red[3];
}

__global__ void att_softmax_kernel(const float* __restrict__ raw, float* __restrict__ att)
{
  int b = threadIdx.x;
  if (b < 4) {
    float r0 = raw[b], r1 = raw[4 + b], r2 = raw[8 + b], r3 = raw[12 + b];
    float m = fmaxf(fmaxf(r0, r1), fmaxf(r2, r3));
    float e0 = expf(r0 - m), e1 = expf(r1 - m), e2 = expf(r2 - m), e3 = expf(r3 - m);
    float inv = 1.0f / (e0 + e1 + e2 + e3);
    att[b] = e0 * inv; att[4 + b] = e1 * inv; att[8 + b] = e2 * inv; att[12 + b] = e3 * inv;
  }
}

// ---------------------------------------------------------------------------
extern "C" void kernel_launch(void* const* d_in, const int* in_sizes, int n_in,
                              void* d_out, int out_size, void* d_ws, size_t ws_size,
                              hipStream_t stream)
{
  const float* x     = (const float*)d_in[0];
  const int*   edges = (const int*)d_in[1];
  const float* proj  = (const float*)d_in[2];
  const float* gcnW  = (const float*)d_in[3];
  const float* gcnB  = (const float*)d_in[4];
  const float* bil   = (const float*)d_in[5];
  const float* invW  = (const float*)d_in[6];
  const float* invB  = (const float*)d_in[7];
  float* out = (float*)d_out;

  // Workspace layout (~179 MB base; +102.4 MB optional x split)
  float* HWB       = (float*)d_ws;                    // NH
  float* dinv      = HWB + NH;                        // NDIM*N
  float* Tbuf      = dinv + NDIM * N_NODES;           // NDIM*IN_F*H_F
  float* att_raw   = Tbuf + (long)NDIM * IN_F * H_F;  // 16
  float* att       = att_raw + 16;                    // 16
  int*   cnt       = (int*)(att + 16);                // NDIM*N
  int*   fill_cnt  = cnt + NDIM * N_NODES;            // NDIM*N
  int*   row_start = fill_cnt + NDIM * N_NODES;       // NDIM*(N+1)
  int*   csr_src   = row_start + NDIM * (N_NODES + 1);// NDIM*E
  __bf16* projTh   = (__bf16*)(csr_src + (long)NDIM * N_EDGE);   // 4*256*512
  __bf16* projTl   = projTh + (long)NDIM * IN_F * H_F;
  __bf16* gcnWTh   = projTl + (long)NDIM * IN_F * H_F;           // 4*256*256
  __bf16* gcnWTl   = gcnWTh + (long)NDIM * H_F * H_F;
  __bf16* bcatTh   = gcnWTl + (long)NDIM * H_F * H_F;            // 4*512*512
  __bf16* bcatTl   = bcatTh + (long)NDIM * OUT_F * 512;
  __bf16* bilTh    = bcatTl + (long)NDIM * OUT_F * 512;          // 256*256
  __bf16* bilTl    = bilTh + (long)H_F * H_F;
  __bf16* Rh       = bilTl + (long)H_F * H_F;                    // NH
  __bf16* Rl       = Rh + NH;
  __bf16* WBh      = Rl + NH;                                    // NH
  __bf16* WBl      = WBh + NH;
  __bf16* xh       = WBl + NH;                                   // optional: N*IN_F
  __bf16* xl       = xh + (long)N_NODES * IN_F;
  const size_t need_x = (size_t)((char*)(xl + (long)N_NODES * IN_F) - (char*)d_ws);
  const bool XS = ws_size >= need_x;   // enough room for split x -> full-DMA G1

  const int MBL = (N_NODES + 127) / 128;              // 391

  // --- CSR build ---
  hipMemsetAsync(cnt, 0, (size_t)2 * NDIM * N_NODES * sizeof(int), stream);
  deg_count_kernel<<<(NDIM * N_EDGE + 255) / 256, 256, 0, stream>>>(edges, cnt, N_EDGE);
  scan_kernel<<<NDIM, 1024, 0, stream>>>(cnt, row_start, dinv);
  fill_kernel<<<(NDIM * N_EDGE + 255) / 256, 256, 0, stream>>>(edges, row_start, fill_cnt,
                                                               csr_src, N_EDGE);

  // --- weight prep (transpose + split) ---
  splitT_kernel<<<(NDIM * IN_F * H_F + 255) / 256, 256, 0, stream>>>(
      proj, projTh, projTl, IN_F, H_F, NDIM * IN_F * H_F);
  splitT_kernel<<<(NDIM * H_F * H_F + 255) / 256, 256, 0, stream>>>(
      gcnW, gcnWTh, gcnWTl, H_F, H_F, NDIM * H_F * H_F);
  splitT_kernel<<<(H_F * H_F + 255) / 256, 256, 0, stream>>>(
      bil, bilTh, bilTl, H_F, H_F, H_F * H_F);

  // --- attention: T_a = proj_a @ bil (fp32-A MFMA path), dot, softmax, Bcat ---
  for (int a = 0; a < NDIM; ++a)
    gemm_k<true><<<dim3(H_F / 128, IN_F / 128), 256, 0, stream>>>(
        proj + (long)a * IN_F * H_F, H_F,
        nullptr, nullptr, 0, nullptr, nullptr, 0, 0,
        bilTh, bilTl,
        Tbuf + (long)a * IN_F * H_F, H_F,
        nullptr, nullptr, nullptr, 0,
        IN_F, H_F, H_F, 0, 0);
  att_dot_kernel<<<16, 256, 0, stream>>>(Tbuf, proj, att_raw);
  att_softmax_kernel<<<1, 64, 0, stream>>>(att_raw, att);
  bcat_kernel<<<(NDIM * OUT_F * 512 + 255) / 256, 256, 0, stream>>>(invW, att, bcatTh, bcatTl);

  // --- optional one-time x split for full-DMA G1 ---
  if (XS)
    splitA_kernel<<<(int)(((long)N_NODES * IN_F + 255) / 256), 256, 0, stream>>>(
        x, xh, xl, (long)N_NODES * IN_F);

  // --- per-dim pipeline ---
  for (int d = 0; d < NDIM; ++d) {
    // G1: R = leaky(x @ proj[d]) -> split bf16 (Rh/Rl).  M=50000 N=256 K=512
    if (XS)
      gemm_k<false><<<dim3(H_F / 128, MBL), 256, 0, stream>>>(
          nullptr, 0,
          xh, xl, IN_F, xh, xl, IN_F, IN_F,
          projTh + (long)d * IN_F * H_F, projTl + (long)d * IN_F * H_F,
          nullptr, 0, nullptr,
          Rh, Rl, H_F,
          N_NODES, H_F, IN_F, 0, 1);
    else
      gemm_k<true><<<dim3(H_F / 128, MBL), 256, 0, stream>>>(
          x, IN_F,
          nullptr, nullptr, 0, nullptr, nullptr, 0, 0,
          projTh + (long)d * IN_F * H_F, projTl + (long)d * IN_F * H_F,
          nullptr, 0, nullptr,
          Rh, Rl, H_F,
          N_NODES, H_F, IN_F, 0, 1);

    // G2: HWB = R @ gcnW[d] (fp32 out for gather).  M=50000 N=256 K=256
    gemm_k<false><<<dim3(H_F / 128, MBL), 256, 0, stream>>>(
        nullptr, 0,
        Rh, Rl, H_F, Rh, Rl, H_F, H_F,
        gcnWTh + (long)d * H_F * H_F, gcnWTl + (long)d * H_F * H_F,
        HWB, H_F, nullptr,
        nullptr, nullptr, 0,
        N_NODES, H_F, H_F, 0, 0);

    // WB = 0.5*bias + selfloop + neighbor gather -> split bf16 (WBh/WBl)
    gather_aggr_kernel<<<N_NODES / 4, 256, 0, stream>>>(
        HWB, csr_src + (long)d * N_EDGE, row_start + d * (N_NODES + 1),
        dinv + d * N_NODES, gcnB + d * H_F, WBh, WBl);

    // G3: out (+)= [WB | R] @ [invW_d ; Wmix_d]   M=50000 N=512 K=512 (kSplit=256)
    // d==0 folds invB (no init kernel, no accumulate read); d==3 applies leaky.
    gemm_k<false><<<dim3(OUT_F / 128, MBL), 256, 0, stream>>>(
        nullptr, 0,
        WBh, WBl, H_F, Rh, Rl, H_F, H_F,
        bcatTh + (long)d * OUT_F * 512, bcatTl + (long)d * OUT_F * 512,
        out, OUT_F, (d == 0) ? invB : nullptr,
        nullptr, nullptr, 0,
        N_NODES, OUT_F, 512, (d == 0) ? 0 : 1, (d == NDIM - 1) ? 1 : 0);
  }

  (void)in_sizes; (void)n_in; (void)out_size; (void)ws_size;
}

// Round 3
// 2738.650 us; speedup vs baseline: 1.0688x; 1.0688x over previous
//
#include <hip/hip_runtime.h>
#include <math.h>

// Problem constants (fixed by the reference setup_inputs).
constexpr int N_NODES = 50000;
constexpr int IN_F    = 512;
constexpr int H_F     = 256;
constexpr int OUT_F   = 512;
constexpr int N_EDGE  = 800000;
constexpr int NDIM    = 4;
constexpr long NH     = (long)N_NODES * H_F;   // 12,800,000

#define LEAKY_SLOPE 0.01f

__device__ __forceinline__ float leaky_f(float v) { return v > 0.0f ? v : LEAKY_SLOPE * v; }

typedef __bf16 bf16x8 __attribute__((ext_vector_type(8)));
typedef float  f32x4  __attribute__((ext_vector_type(4)));

// Per-256-k-chunk A base pointers (hi/lo split). Lets one GEMM read
// [WB0|R0|WB1|R1|WB2|R2|WB3|R3] as a K=2048 A without concatenating.
struct PtrTab { const __bf16* h[8]; const __bf16* l[8]; };

// async global->LDS, 16B per lane: LDS dest = wave-uniform base + lane*16.
__device__ __forceinline__ void gload16(const void* g, void* s) {
  __builtin_amdgcn_global_load_lds(
      (const __attribute__((address_space(1))) void*)g,
      (__attribute__((address_space(3))) void*)s, 16, 0, 0);
}

// ---------------------------------------------------------------------------
// Split-bf16 MFMA GEMM with 2-phase double-buffered DMA pipeline.
//  - LDS tiles [128][32] bf16, linear (64B rows) for global_load_lds.
//  - chunk-XOR swizzle (16B granularity): physical_chunk = q ^ ((row>>1)&3),
//    applied to the GLOBAL source address on stage and to the ds_read_b128
//    address on fragment load (both-sides-or-neither). 8-way conflict -> free
//    2-way.
//  - K-loop: STAGE(next buf) -> ds_read(cur)+MFMA(cur) -> __syncthreads().
//  - bijective XCD swizzle on the flattened block id (col-fastest work ids:
//    blocks sharing an A row-panel land on one XCD's L2).
//  - AF32=true: A fp32; float4s prefetched to regs for tile t+1, split and
//    ds_written (swizzled) after tile t's MFMA.
// Epilogue: optional bias vector, fp32 accumulate, leaky; store fp32 (C) or
// split-bf16 (Oh/Ol).
// ---------------------------------------------------------------------------
template<bool AF32>
__global__ __launch_bounds__(256) void gemm_k(
    const float* __restrict__ Af, int ldaf,
    PtrTab at, int lda,
    const __bf16* __restrict__ BhT, const __bf16* __restrict__ BlT, int ldb,
    float* __restrict__ C, int ldc,
    const float* __restrict__ biasVec,
    __bf16* __restrict__ Oh, __bf16* __restrict__ Ol, int ldo,
    int M, int N, int K, int accumulate, int leaky)
{
  __shared__ __bf16 AshF[2][4096];   // [buf][128 rows * 32 k]
  __shared__ __bf16 AslF[2][4096];
  __shared__ __bf16 BshF[2][4096];
  __shared__ __bf16 BslF[2][4096];

  const int tid  = threadIdx.x;
  const int lane = tid & 63;
  const int wid  = tid >> 6;
  const int wm   = wid & 1;
  const int wn   = wid >> 1;
  const int l15  = lane & 15;
  const int quad = lane >> 4;

  // Bijective XCD-aware block remap (any nwg).
  const int nwg = (int)(gridDim.x * gridDim.y);
  const int hw  = (int)(blockIdx.y * gridDim.x + blockIdx.x);
  const int xcd = hw & 7, idx = hw >> 3;
  const int q8 = nwg >> 3, r8 = nwg & 7;
  const int wk = (xcd < r8 ? xcd * (q8 + 1) : r8 * (q8 + 1) + (xcd - r8) * q8) + idx;
  const int col0 = (wk % (int)gridDim.x) * 128;
  const int row0 = (wk / (int)gridDim.x) * 128;

  f32x4 acc[4][4] = {};
  const int nkt = K >> 5;

  float4 areg[4];   // AF32 prefetch regs

  // ---- staging helpers -----------------------------------------------------
  auto stageB = [&](int buf, int kt) {
    const int kb = kt << 5;
    #pragma unroll
    for (int p = 0; p < 2; ++p) {
      const int c  = tid + p * 256;
      const int rr = c >> 2;
      const int sw = ((c & 3) ^ ((rr >> 1) & 3)) * 8;
      const size_t go = (size_t)(col0 + rr) * ldb + kb + sw;
      gload16(BhT + go, &BshF[buf][c * 8]);
      gload16(BlT + go, &BslF[buf][c * 8]);
    }
  };
  auto stageA = [&](int buf, int kt) {
    const int ch = kt >> 3;
    const __bf16* __restrict__ Ah = at.h[ch];
    const __bf16* __restrict__ Al = at.l[ch];
    const int ka = (kt & 7) << 5;
    #pragma unroll
    for (int p = 0; p < 2; ++p) {
      const int c  = tid + p * 256;
      const int rr = c >> 2;
      const int sw = ((c & 3) ^ ((rr >> 1) & 3)) * 8;
      int row = row0 + rr; row = row < M ? row : M - 1;
      const size_t go = (size_t)row * lda + ka + sw;
      gload16(Ah + go, &AshF[buf][c * 8]);
      gload16(Al + go, &AslF[buf][c * 8]);
    }
  };
  auto loadA32 = [&](int kt) {
    #pragma unroll
    for (int p = 0; p < 4; ++p) {
      const int m = (tid >> 3) + p * 32;
      int row = row0 + m; row = row < M ? row : M - 1;
      areg[p] = *(const float4*)(Af + (size_t)row * ldaf + (kt << 5) + (tid & 7) * 4);
    }
  };
  auto writeA32 = [&](int buf) {
    const int q16 = (tid & 7) >> 1;     // logical 16B chunk (0..3)
    const int sub = (tid & 1) * 4;      // low/high half of the chunk
    #pragma unroll
    for (int p = 0; p < 4; ++p) {
      const int m = (tid >> 3) + p * 32;
      const float f[4] = {areg[p].x, areg[p].y, areg[p].z, areg[p].w};
      union { __bf16 b[4]; short4 s; } hh, ll;
      #pragma unroll
      for (int i = 0; i < 4; ++i) {
        const __bf16 hb = (__bf16)f[i];
        hh.b[i] = hb;
        ll.b[i] = (__bf16)(f[i] - (float)hb);
      }
      const int off = m * 32 + ((q16 ^ ((m >> 1) & 3)) * 8) + sub;
      *(short4*)&AshF[buf][off] = hh.s;
      *(short4*)&AslF[buf][off] = ll.s;
    }
  };

  // ---- prologue: fill buffer 0 --------------------------------------------
  if constexpr (AF32) {
    loadA32(0);
    stageB(0, 0);
    writeA32(0);
  } else {
    stageA(0, 0);
    stageB(0, 0);
  }
  __syncthreads();   // drains vmcnt (DMA) + lgkmcnt (ds_writes), then barrier

  // ---- main loop: STAGE(next) || compute(cur) ------------------------------
  int cur = 0;
  for (int kt = 0; kt < nkt; ++kt) {
    const bool more = (kt + 1 < nkt);
    if constexpr (AF32) {
      if (more) { loadA32(kt + 1); stageB(cur ^ 1, kt + 1); }
    } else {
      if (more) { stageA(cur ^ 1, kt + 1); stageB(cur ^ 1, kt + 1); }
    }

    bf16x8 ah[4], al[4], bh[4], bl[4];
    #pragma unroll
    for (int t = 0; t < 4; ++t) {
      const int ar = wm * 64 + t * 16 + l15;
      const int br = wn * 64 + t * 16 + l15;
      const int as = ar * 32 + ((quad ^ ((ar >> 1) & 3)) * 8);
      const int bs = br * 32 + ((quad ^ ((br >> 1) & 3)) * 8);
      ah[t] = *(const bf16x8*)&AshF[cur][as];
      al[t] = *(const bf16x8*)&AslF[cur][as];
      bh[t] = *(const bf16x8*)&BshF[cur][bs];
      bl[t] = *(const bf16x8*)&BslF[cur][bs];
    }
    #pragma unroll
    for (int mt = 0; mt < 4; ++mt)
      #pragma unroll
      for (int nt = 0; nt < 4; ++nt) {
        acc[mt][nt] = __builtin_amdgcn_mfma_f32_16x16x32_bf16(ah[mt], bh[nt], acc[mt][nt], 0, 0, 0);
        acc[mt][nt] = __builtin_amdgcn_mfma_f32_16x16x32_bf16(ah[mt], bl[nt], acc[mt][nt], 0, 0, 0);
        acc[mt][nt] = __builtin_amdgcn_mfma_f32_16x16x32_bf16(al[mt], bh[nt], acc[mt][nt], 0, 0, 0);
      }

    if constexpr (AF32) {
      if (more) writeA32(cur ^ 1);
    }
    __syncthreads();   // vmcnt(0)+lgkmcnt(0) drain + barrier: next buf ready
    cur ^= 1;
  }

  // ---- epilogue: C/D layout col=lane&15, row=quad*4+reg --------------------
  #pragma unroll
  for (int mt = 0; mt < 4; ++mt)
    #pragma unroll
    for (int nt = 0; nt < 4; ++nt) {
      const int col = col0 + wn * 64 + nt * 16 + l15;
      const float bv = biasVec ? biasVec[col] : 0.0f;
      #pragma unroll
      for (int r = 0; r < 4; ++r) {
        const int row = row0 + wm * 64 + mt * 16 + quad * 4 + r;
        if (row < M) {
          float v = acc[mt][nt][r] + bv;
          if (accumulate) v += C[(size_t)row * ldc + col];
          if (leaky) v = leaky_f(v);
          if (Oh) {
            const __bf16 hv = (__bf16)v;
            Oh[(size_t)row * ldo + col] = hv;
            Ol[(size_t)row * ldo + col] = (__bf16)(v - (float)hv);
          } else {
            C[(size_t)row * ldc + col] = v;
          }
        }
      }
    }
}

// ---------------------------------------------------------------------------
// Weight prep: transpose + hi/lo split.  B:[Z][Kd][Nd] -> out:[Z][Nd][Kd]
// ---------------------------------------------------------------------------
__global__ void splitT_kernel(const float* __restrict__ B, __bf16* __restrict__ h,
                              __bf16* __restrict__ l, int Kd, int Nd, int total)
{
  int i = blockIdx.x * 256 + threadIdx.x;
  if (i >= total) return;
  int z   = i / (Kd * Nd);
  int rem = i - z * (Kd * Nd);
  int k = rem / Nd;
  int n = rem - k * Nd;
  float v = B[i];
  __bf16 hv = (__bf16)v;
  long o = (long)z * Kd * Nd + (long)n * Kd + k;
  h[o] = hv;
  l[o] = (__bf16)(v - (float)hv);
}

// Non-transposing split (for x -> xh/xl)
__global__ void splitA_kernel(const float* __restrict__ A, __bf16* __restrict__ h,
                              __bf16* __restrict__ l, long total)
{
  long i = (long)blockIdx.x * 256 + threadIdx.x;
  if (i >= total) return;
  float v = A[i];
  __bf16 hv = (__bf16)v;
  h[i] = hv;
  l[i] = (__bf16)(v - (float)hv);
}

// Bcat stacked over dims: out layout [n][d*512 + k]  (n rows of K=2048).
// k<H: invW[d*H+k][n]; else 0.5*sum_b att[d*4+b]*invW[b*H+(k-H)][n]
__global__ void bcat_kernel(const float* __restrict__ invW, const float* __restrict__ att,
                            __bf16* __restrict__ h, __bf16* __restrict__ l)
{
  int i = blockIdx.x * 256 + threadIdx.x;           // over 4*512*512
  if (i >= NDIM * OUT_F * 512) return;
  int d   = i >> 18;
  int rem = i & 262143;
  int n = rem >> 9;
  int k = rem & 511;
  float v;
  if (k < H_F) {
    v = invW[(long)(d * H_F + k) * OUT_F + n];
  } else {
    float s = 0.f;
    #pragma unroll
    for (int b = 0; b < 4; ++b)
      s += att[d * 4 + b] * invW[(long)(b * H_F + (k - H_F)) * OUT_F + n];
    v = 0.5f * s;
  }
  __bf16 hv = (__bf16)v;
  long o = (long)n * (NDIM * 512) + d * 512 + k;
  h[o] = hv;
  l[o] = (__bf16)(v - (float)hv);
}

// ---------------------------------------------------------------------------
// CSR build: count in-degrees, scan to row offsets, fill src buckets.
// ---------------------------------------------------------------------------
__global__ void deg_count_kernel(const int* __restrict__ edges, int* __restrict__ cnt, int E)
{
  int i = blockIdx.x * 256 + threadIdx.x;
  if (i >= NDIM * E) return;
  int d = i / E;
  int e = i - d * E;
  int t = edges[(long)d * 2 * E + E + e];
  atomicAdd(&cnt[d * N_NODES + t], 1);
}

__global__ __launch_bounds__(1024) void scan_kernel(const int* __restrict__ cnt,
                                                    int* __restrict__ row_start,
                                                    float* __restrict__ dinv)
{
  const int d    = blockIdx.x;
  const int tid  = threadIdx.x;
  const int lane = tid & 63;
  const int wid  = tid >> 6;
  __shared__ int wsum[16];
  __shared__ int carry_s;
  if (tid == 0) carry_s = 0;
  __syncthreads();
  for (int base = 0; base < N_NODES; base += 1024) {
    int i = base + tid;
    int v = (i < N_NODES) ? cnt[d * N_NODES + i] : 0;
    if (i < N_NODES) dinv[d * N_NODES + i] = sqrtf(0.5f / (float)(v + 1));
    int incl = v;
    #pragma unroll
    for (int off = 1; off < 64; off <<= 1) {
      int nb = __shfl_up(incl, off, 64);
      if (lane >= off) incl += nb;
    }
    if (lane == 63) wsum[wid] = incl;
    __syncthreads();
    if (wid == 0 && lane < 16) {
      int s = wsum[lane];
      #pragma unroll
      for (int off = 1; off < 16; off <<= 1) {
        int nb = __shfl_up(s, off, 16);
        if (lane >= off) s += nb;
      }
      wsum[lane] = s;
    }
    __syncthreads();
    int waveoff = (wid == 0) ? 0 : wsum[wid - 1];
    if (i < N_NODES) row_start[d * (N_NODES + 1) + i] = carry_s + waveoff + incl - v;
    __syncthreads();
    if (tid == 1023) carry_s += wsum[15];
    __syncthreads();
  }
  if (tid == 0) row_start[d * (N_NODES + 1) + N_NODES] = carry_s;
}

__global__ void fill_kernel(const int* __restrict__ edges, const int* __restrict__ row_start,
                            int* __restrict__ fill_cnt, int* __restrict__ csr_src, int E)
{
  int i = blockIdx.x * 256 + threadIdx.x;
  if (i >= NDIM * E) return;
  int d = i / E;
  int e = i - d * E;
  int s = edges[(long)d * 2 * E + e];
  int t = edges[(long)d * 2 * E + E + e];
  int pos = row_start[d * (N_NODES + 1) + t] + atomicAdd(&fill_cnt[d * N_NODES + t], 1);
  csr_src[(long)d * E + pos] = s;
}

// ---------------------------------------------------------------------------
// Gather aggregation: one wave per dst node (no atomics), 2-edge unroll,
// emits WB directly split bf16.
// ---------------------------------------------------------------------------
__global__ __launch_bounds__(256) void gather_aggr_kernel(
    const float* __restrict__ hw, const int* __restrict__ csr_src,
    const int* __restrict__ row_start, const float* __restrict__ dinv,
    const float* __restrict__ bias, __bf16* __restrict__ Wh, __bf16* __restrict__ Wl)
{
  const int n = blockIdx.x * 4 + (threadIdx.x >> 6);
  const int lane = threadIdx.x & 63;
  const float dt = dinv[n];
  const float sl = dt * dt;
  const float4 b = *(const float4*)(bias + lane * 4);
  const float4 h = *(const float4*)(hw + (size_t)n * H_F + lane * 4);
  float4 a0 = make_float4(0.5f * b.x + sl * h.x, 0.5f * b.y + sl * h.y,
                          0.5f * b.z + sl * h.z, 0.5f * b.w + sl * h.w);
  float4 a1 = make_float4(0.f, 0.f, 0.f, 0.f);
  const int beg = row_start[n];
  const int end = row_start[n + 1];
  int j = beg;
  for (; j + 2 <= end; j += 2) {
    const int s0 = csr_src[j];
    const int s1 = csr_src[j + 1];
    const float nm0 = dt * dinv[s0];
    const float nm1 = dt * dinv[s1];
    const float4 v0 = *(const float4*)(hw + (size_t)s0 * H_F + lane * 4);
    const float4 v1 = *(const float4*)(hw + (size_t)s1 * H_F + lane * 4);
    a0.x = fmaf(nm0, v0.x, a0.x); a0.y = fmaf(nm0, v0.y, a0.y);
    a0.z = fmaf(nm0, v0.z, a0.z); a0.w = fmaf(nm0, v0.w, a0.w);
    a1.x = fmaf(nm1, v1.x, a1.x); a1.y = fmaf(nm1, v1.y, a1.y);
    a1.z = fmaf(nm1, v1.z, a1.z); a1.w = fmaf(nm1, v1.w, a1.w);
  }
  if (j < end) {
    const int s0 = csr_src[j];
    const float nm0 = dt * dinv[s0];
    const float4 v0 = *(const float4*)(hw + (size_t)s0 * H_F + lane * 4);
    a0.x = fmaf(nm0, v0.x, a0.x); a0.y = fmaf(nm0, v0.y, a0.y);
    a0.z = fmaf(nm0, v0.z, a0.z); a0.w = fmaf(nm0, v0.w, a0.w);
  }
  const float av[4] = {a0.x + a1.x, a0.y + a1.y, a0.z + a1.z, a0.w + a1.w};
  union { __bf16 b[4]; short4 s; } H, L;
  #pragma unroll
  for (int i = 0; i < 4; ++i) {
    const __bf16 hv = (__bf16)av[i];
    H.b[i] = hv;
    L.b[i] = (__bf16)(av[i] - (float)hv);
  }
  *(short4*)(Wh + (size_t)n * H_F + lane * 4) = H.s;
  *(short4*)(Wl + (size_t)n * H_F + lane * 4) = L.s;
}

// ---------------------------------------------------------------------------
// Attention small kernels
// ---------------------------------------------------------------------------
__global__ void att_dot_kernel(const float* __restrict__ T, const float* __restrict__ P,
                               float* __restrict__ out16)
{
  const int a = blockIdx.x >> 2;
  const int b = blockIdx.x & 3;
  const float* ta = T + (long)a * (IN_F * H_F);
  const float* pb = P + (long)b * (IN_F * H_F);
  float s = 0.f;
  for (int i = threadIdx.x; i < IN_F * H_F; i += 256) s += ta[i] * pb[i];
  #pragma unroll
  for (int off = 32; off > 0; off >>= 1) s += __shfl_down(s, off, 64);
  __shared__ float red[4];
  if ((threadIdx.x & 63) == 0) red[threadIdx.x >> 6] = s;
  __syncthreads();
  if (threadIdx.x == 0) out16[blockIdx.x] = red[0] + red[1] + red[2] + red[3];
}

__global__ void att_softmax_kernel(const float* __restrict__ raw, float* __restrict__ att)
{
  int b = threadIdx.x;
  if (b < 4) {
    float r0 = raw[b], r1 = raw[4 + b], r2 = raw[8 + b], r3 = raw[12 + b];
    float m = fmaxf(fmaxf(r0, r1), fmaxf(r2, r3));
    float e0 = expf(r0 - m), e1 = expf(r1 - m), e2 = expf(r2 - m), e3 = expf(r3 - m);
    float inv = 1.0f / (e0 + e1 + e2 + e3);
    att[b] = e0 * inv; att[4 + b] = e1 * inv; att[8 + b] = e2 * inv; att[12 + b] = e3 * inv;
  }
}

// ---------------------------------------------------------------------------
extern "C" void kernel_launch(void* const* d_in, const int* in_sizes, int n_in,
                              void* d_out, int out_size, void* d_ws, size_t ws_size,
                              hipStream_t stream)
{
  const float* x     = (const float*)d_in[0];
  const int*   edges = (const int*)d_in[1];
  const float* proj  = (const float*)d_in[2];
  const float* gcnW  = (const float*)d_in[3];
  const float* gcnB  = (const float*)d_in[4];
  const float* bil   = (const float*)d_in[5];
  const float* invW  = (const float*)d_in[6];
  const float* invB  = (const float*)d_in[7];
  float* out = (float*)d_out;

  // ---- workspace layout (fixed part ~77 MB) ----
  float* HWB       = (float*)d_ws;                    // NH
  float* dinv      = HWB + NH;                        // NDIM*N
  float* Tbuf      = dinv + NDIM * N_NODES;           // NDIM*IN_F*H_F
  float* att_raw   = Tbuf + (long)NDIM * IN_F * H_F;  // 16
  float* att       = att_raw + 16;                    // 16
  int*   cnt       = (int*)(att + 16);                // NDIM*N
  int*   fill_cnt  = cnt + NDIM * N_NODES;            // NDIM*N
  int*   row_start = fill_cnt + NDIM * N_NODES;       // NDIM*(N+1)
  int*   csr_src   = row_start + NDIM * (N_NODES + 1);// NDIM*E
  __bf16* projTh   = (__bf16*)(csr_src + (long)NDIM * N_EDGE);   // 4*256*512
  __bf16* projTl   = projTh + (long)NDIM * IN_F * H_F;
  __bf16* gcnWTh   = projTl + (long)NDIM * IN_F * H_F;           // 4*256*256
  __bf16* gcnWTl   = gcnWTh + (long)NDIM * H_F * H_F;
  __bf16* bcatTh   = gcnWTl + (long)NDIM * H_F * H_F;            // [n][2048] stacked
  __bf16* bcatTl   = bcatTh + (long)NDIM * OUT_F * 512;
  __bf16* bilTh    = bcatTl + (long)NDIM * OUT_F * 512;          // 256*256
  __bf16* bilTl    = bilTh + (long)H_F * H_F;
  __bf16* dynBase  = bilTl + (long)H_F * H_F;

  const size_t base_bytes  = (size_t)((char*)dynBase - (char*)d_ws);
  const size_t need_merged = base_bytes + (size_t)16 * NH * sizeof(__bf16); // R,WB h/l x4 dims
  const size_t need_xs     = need_merged + (size_t)2 * N_NODES * IN_F * sizeof(__bf16);
  const bool MERGED = ws_size >= need_merged;
  const bool XS     = ws_size >= need_xs;
  const int  RD     = MERGED ? NDIM : 1;              // dims of R/WB kept live

  __bf16* Rh  = dynBase;
  __bf16* Rl  = Rh + (long)RD * NH;
  __bf16* WBh = Rl + (long)RD * NH;
  __bf16* WBl = WBh + (long)RD * NH;
  __bf16* xh  = WBl + (long)RD * NH;                  // only valid if XS
  __bf16* xl  = xh + (long)N_NODES * IN_F;

  const int MBL = (N_NODES + 127) / 128;              // 391
  PtrTab empty{};

  // --- CSR build ---
  hipMemsetAsync(cnt, 0, (size_t)2 * NDIM * N_NODES * sizeof(int), stream);
  deg_count_kernel<<<(NDIM * N_EDGE + 255) / 256, 256, 0, stream>>>(edges, cnt, N_EDGE);
  scan_kernel<<<NDIM, 1024, 0, stream>>>(cnt, row_start, dinv);
  fill_kernel<<<(NDIM * N_EDGE + 255) / 256, 256, 0, stream>>>(edges, row_start, fill_cnt,
                                                               csr_src, N_EDGE);

  // --- weight prep (transpose + split) ---
  splitT_kernel<<<(NDIM * IN_F * H_F + 255) / 256, 256, 0, stream>>>(
      proj, projTh, projTl, IN_F, H_F, NDIM * IN_F * H_F);
  splitT_kernel<<<(NDIM * H_F * H_F + 255) / 256, 256, 0, stream>>>(
      gcnW, gcnWTh, gcnWTl, H_F, H_F, NDIM * H_F * H_F);
  splitT_kernel<<<(H_F * H_F + 255) / 256, 256, 0, stream>>>(
      bil, bilTh, bilTl, H_F, H_F, H_F * H_F);

  // --- attention: T_a = proj_a @ bil, dot, softmax, Bcat ---
  for (int a = 0; a < NDIM; ++a)
    gemm_k<true><<<dim3(H_F / 128, IN_F / 128), 256, 0, stream>>>(
        proj + (long)a * IN_F * H_F, H_F,
        empty, 0,
        bilTh, bilTl, H_F,
        Tbuf + (long)a * IN_F * H_F, H_F,
        nullptr, nullptr, nullptr, 0,
        IN_F, H_F, H_F, 0, 0);
  att_dot_kernel<<<16, 256, 0, stream>>>(Tbuf, proj, att_raw);
  att_softmax_kernel<<<1, 64, 0, stream>>>(att_raw, att);
  bcat_kernel<<<(NDIM * OUT_F * 512 + 255) / 256, 256, 0, stream>>>(invW, att, bcatTh, bcatTl);

  if (XS)
    splitA_kernel<<<(int)(((long)N_NODES * IN_F + 255) / 256), 256, 0, stream>>>(
        x, xh, xl, (long)N_NODES * IN_F);

  // --- MERGED: G1 for all dims up front: R_d = leaky(x @ proj[d]) ---
  if (MERGED) {
    for (int d = 0; d < NDIM; ++d) {
      if (XS) {
        PtrTab t{};
        for (int c = 0; c < 8; ++c) { t.h[c] = xh + (c & 1) * 256; t.l[c] = xl + (c & 1) * 256; }
        gemm_k<false><<<dim3(H_F / 128, MBL), 256, 0, stream>>>(
            nullptr, 0, t, IN_F,
            projTh + (long)d * IN_F * H_F, projTl + (long)d * IN_F * H_F, IN_F,
            nullptr, 0, nullptr,
            Rh + (long)d * NH, Rl + (long)d * NH, H_F,
            N_NODES, H_F, IN_F, 0, 1);
      } else {
        gemm_k<true><<<dim3(H_F / 128, MBL), 256, 0, stream>>>(
            x, IN_F, empty, 0,
            projTh + (long)d * IN_F * H_F, projTl + (long)d * IN_F * H_F, IN_F,
            nullptr, 0, nullptr,
            Rh + (long)d * NH, Rl + (long)d * NH, H_F,
            N_NODES, H_F, IN_F, 0, 1);
      }
    }
  }

  // --- per-dim: (fallback: G1), G2, gather, (fallback: G3 accumulate) ---
  for (int d = 0; d < NDIM; ++d) {
    const long rslot = MERGED ? d : 0;
    if (!MERGED) {
      gemm_k<true><<<dim3(H_F / 128, MBL), 256, 0, stream>>>(
          x, IN_F, empty, 0,
          projTh + (long)d * IN_F * H_F, projTl + (long)d * IN_F * H_F, IN_F,
          nullptr, 0, nullptr,
          Rh, Rl, H_F,
          N_NODES, H_F, IN_F, 0, 1);
    }
    // G2: HWB = R_d @ gcnW[d] (fp32 out for gather)
    {
      PtrTab t{};
      for (int c = 0; c < 8; ++c) { t.h[c] = Rh + rslot * NH; t.l[c] = Rl + rslot * NH; }
      gemm_k<false><<<dim3(H_F / 128, MBL), 256, 0, stream>>>(
          nullptr, 0, t, H_F,
          gcnWTh + (long)d * H_F * H_F, gcnWTl + (long)d * H_F * H_F, H_F,
          HWB, H_F, nullptr,
          nullptr, nullptr, 0,
          N_NODES, H_F, H_F, 0, 0);
    }
    // WB_d = 0.5*bias + selfloop + neighbor gather -> split bf16
    gather_aggr_kernel<<<N_NODES / 4, 256, 0, stream>>>(
        HWB, csr_src + (long)d * N_EDGE, row_start + d * (N_NODES + 1),
        dinv + d * N_NODES, gcnB + d * H_F,
        WBh + rslot * NH, WBl + rslot * NH);

    if (!MERGED) {
      // fallback G3_d: out (+)= [WB|R_d] @ Bcat_d   K=512
      PtrTab t{};
      for (int c = 0; c < 8; ++c) {
        t.h[c] = (c & 1) ? Rh : WBh;
        t.l[c] = (c & 1) ? Rl : WBl;
      }
      gemm_k<false><<<dim3(OUT_F / 128, MBL), 256, 0, stream>>>(
          nullptr, 0, t, H_F,
          bcatTh + (long)d * 512, bcatTl + (long)d * 512, NDIM * 512,
          out, OUT_F, (d == 0) ? invB : nullptr,
          nullptr, nullptr, 0,
          N_NODES, OUT_F, 512, (d == 0) ? 0 : 1, (d == NDIM - 1) ? 1 : 0);
    }
  }

  // --- merged G3: out = leaky(invB + [WB0|R0|...|WB3|R3] @ BcatStack)  K=2048
  if (MERGED) {
    PtrTab t{};
    for (int c = 0; c < 8; ++c) {
      const long dd = c >> 1;
      t.h[c] = (c & 1) ? Rh + dd * NH : WBh + dd * NH;
      t.l[c] = (c & 1) ? Rl + dd * NH : WBl + dd * NH;
    }
    gemm_k<false><<<dim3(OUT_F / 128, MBL), 256, 0, stream>>>(
        nullptr, 0, t, H_F,
        bcatTh, bcatTl, NDIM * 512,
        out, OUT_F, invB,
        nullptr, nullptr, 0,
        N_NODES, OUT_F, NDIM * 512, 0, 1);
  }

  (void)in_sizes; (void)n_in; (void)out_size;
}

// Round 5
// 2540.660 us; speedup vs baseline: 1.1521x; 1.0779x over previous
//
#include <hip/hip_runtime.h>
#include <math.h>

// Problem constants (fixed by the reference setup_inputs).
constexpr int N_NODES = 50000;
constexpr int M_PAD   = 50048;             // 391 * 128 (row-padded for tiled A)
constexpr int IN_F    = 512;
constexpr int H_F     = 256;
constexpr int OUT_F   = 512;
constexpr int N_EDGE  = 800000;
constexpr int NDIM    = 4;
constexpr long NH     = (long)N_NODES * H_F;

#define LEAKY_SLOPE 0.01f

__device__ __forceinline__ float leaky_f(float v) { return v > 0.0f ? v : LEAKY_SLOPE * v; }

typedef __bf16 bf16x8 __attribute__((ext_vector_type(8)));
typedef float  f32x4  __attribute__((ext_vector_type(4)));

// Tiled operand layout ("tile image"): a [128 rows][32 k] bf16 tile stored as
// 4096 contiguous elements: off = (row&127)*32 + (k&31). Buffer of tiles:
// [rowblock][kchunk][4096]. A fragment load (16 rows x 16B at col quad*8) is
// then one fully-coalesced 1KB global_load_dwordx4 per wave.

// Bijective XCD-aware block remap: consecutive work ids (col-fastest) land on
// one XCD so the col-blocks sharing an A row-panel share that XCD's L2.
__device__ __forceinline__ void swz_block(int& mb, int& nb) {
  const int nwg = (int)(gridDim.x * gridDim.y);
  const int hw  = (int)(blockIdx.y * gridDim.x + blockIdx.x);
  const int xcd = hw & 7, idx = hw >> 3;
  const int q8 = nwg >> 3, r8 = nwg & 7;
  const int wk = (xcd < r8 ? xcd * (q8 + 1) : r8 * (q8 + 1) + (xcd - r8) * q8) + idx;
  nb = wk % (int)gridDim.x;
  mb = wk / (int)gridDim.x;
}

// ---------------------------------------------------------------------------
// Streaming split-bf16 MFMA GEMM: NO LDS, NO barriers. Both operands pre-split
// hi/lo bf16 in tiled layout; fragments stream L2->VGPR as coalesced 1KB wave
// loads; depth-1 manual prefetch (two named frag sets); compiler inserts
// counted waitcnt; 8+ waves/CU hide the rest.
// C = maybe_leaky(maybe_accum + bias + A@B), or split-bf16 tiled out (Oh/Ol).
// 128x128 block, 4 waves (2x2), wave tile 64x64, 3 MFMA per product (hh+hl+lh).
// ---------------------------------------------------------------------------
__global__ __launch_bounds__(256, 2) void gemm_s(
    const __bf16* __restrict__ Ah, const __bf16* __restrict__ Al, int kcTotA, int kcOffA,
    const __bf16* __restrict__ Bh, const __bf16* __restrict__ Bl, int kcTotB, int kcOffB,
    float* __restrict__ C, int ldc, const float* __restrict__ biasVec,
    __bf16* __restrict__ Oh, __bf16* __restrict__ Ol, int kcTotO, int kcOffO,
    int M, int K, int accumulate, int leaky)
{
  const int tid  = threadIdx.x;
  const int lane = tid & 63;
  const int wid  = tid >> 6;
  const int wm   = wid & 1;
  const int wn   = wid >> 1;
  const int l15  = lane & 15;
  const int quad = lane >> 4;

  int mb, nb;
  swz_block(mb, nb);
  const int row0 = mb * 128;
  const int col0 = nb * 128;

  const size_t aB = ((size_t)mb * kcTotA + kcOffA) * 4096 + (size_t)(wm * 64 + l15) * 32 + quad * 8;
  const size_t bB = ((size_t)nb * kcTotB + kcOffB) * 4096 + (size_t)(wn * 64 + l15) * 32 + quad * 8;

  f32x4 acc[4][4] = {};
  const int nkt = K >> 5;            // even at every call site

  bf16x8 a0h[4], a0l[4], b0h[4], b0l[4];
  bf16x8 a1h[4], a1l[4], b1h[4], b1l[4];

  auto load = [&](bf16x8* ah, bf16x8* al, bf16x8* bh, bf16x8* bl, int kt) {
    const size_t ka = aB + (size_t)kt * 4096;
    const size_t kb = bB + (size_t)kt * 4096;
    #pragma unroll
    for (int t = 0; t < 4; ++t) {
      ah[t] = *(const bf16x8*)(Ah + ka + t * 512);
      al[t] = *(const bf16x8*)(Al + ka + t * 512);
      bh[t] = *(const bf16x8*)(Bh + kb + t * 512);
      bl[t] = *(const bf16x8*)(Bl + kb + t * 512);
    }
  };
  auto step = [&](bf16x8* ah, bf16x8* al, bf16x8* bh, bf16x8* bl) {
    #pragma unroll
    for (int mt = 0; mt < 4; ++mt)
      #pragma unroll
      for (int nt = 0; nt < 4; ++nt) {
        acc[mt][nt] = __builtin_amdgcn_mfma_f32_16x16x32_bf16(ah[mt], bh[nt], acc[mt][nt], 0, 0, 0);
        acc[mt][nt] = __builtin_amdgcn_mfma_f32_16x16x32_bf16(ah[mt], bl[nt], acc[mt][nt], 0, 0, 0);
        acc[mt][nt] = __builtin_amdgcn_mfma_f32_16x16x32_bf16(al[mt], bh[nt], acc[mt][nt], 0, 0, 0);
      }
  };

  load(a0h, a0l, b0h, b0l, 0);
  for (int kt = 0; kt < nkt; kt += 2) {
    load(a1h, a1l, b1h, b1l, kt + 1);          // nkt even -> kt+1 < nkt always
    step(a0h, a0l, b0h, b0l);
    if (kt + 2 < nkt) load(a0h, a0l, b0h, b0l, kt + 2);
    step(a1h, a1l, b1h, b1l);
  }

  // Epilogue: C/D layout col=lane&15, row=quad*4+reg
  #pragma unroll
  for (int mt = 0; mt < 4; ++mt)
    #pragma unroll
    for (int nt = 0; nt < 4; ++nt) {
      const int col = col0 + wn * 64 + nt * 16 + l15;
      const float bv = biasVec ? biasVec[col] : 0.0f;
      #pragma unroll
      for (int r = 0; r < 4; ++r) {
        const int row = row0 + wm * 64 + mt * 16 + quad * 4 + r;
        if (row < M) {
          float v = acc[mt][nt][r] + bv;
          if (accumulate) v += C[(size_t)row * ldc + col];
          if (leaky) v = leaky_f(v);
          if (Oh) {
            const size_t o = ((size_t)mb * kcTotO + kcOffO + (col >> 5)) * 4096
                           + (size_t)(row & 127) * 32 + (col & 31);
            const __bf16 hv = (__bf16)v;
            Oh[o] = hv;
            Ol[o] = (__bf16)(v - (float)hv);
          } else {
            C[(size_t)row * ldc + col] = v;
          }
        }
      }
    }
}

// async global->LDS (used only by the AF32 fallback kernel, proven in round 3)
__device__ __forceinline__ void gload16(const void* g, void* s) {
  __builtin_amdgcn_global_load_lds(
      (const __attribute__((address_space(1))) void*)g,
      (__attribute__((address_space(3))) void*)s, 16, 0, 0);
}

// ---------------------------------------------------------------------------
// AF32 LDS GEMM (round-3 structure verbatim, __syncthreads only): A fp32, B
// linear [n][k] pre-split. Used for attention (tiny) and G1 when no room to
// pre-split x. Out: fp32 C or tiled split-bf16.
// ---------------------------------------------------------------------------
__global__ __launch_bounds__(256) void gemm_af32(
    const float* __restrict__ Af, int ldaf,
    const __bf16* __restrict__ BhT, const __bf16* __restrict__ BlT, int ldb,
    float* __restrict__ C, int ldc,
    __bf16* __restrict__ Oh, __bf16* __restrict__ Ol, int kcTotO, int kcOffO,
    int M, int K, int leaky)
{
  __shared__ __bf16 AshF[2][4096];
  __shared__ __bf16 AslF[2][4096];
  __shared__ __bf16 BshF[2][4096];
  __shared__ __bf16 BslF[2][4096];

  const int tid  = threadIdx.x;
  const int lane = tid & 63;
  const int wid  = tid >> 6;
  const int wm   = wid & 1;
  const int wn   = wid >> 1;
  const int l15  = lane & 15;
  const int quad = lane >> 4;

  int mb, nb;
  swz_block(mb, nb);
  const int row0 = mb * 128;
  const int col0 = nb * 128;

  f32x4 acc[4][4] = {};
  const int nkt = K >> 5;
  float4 areg[4];

  auto stageB = [&](int buf, int kt) {
    const int kb = kt << 5;
    #pragma unroll
    for (int p = 0; p < 2; ++p) {
      const int c  = tid + p * 256;
      const int rr = c >> 2;
      const int sw = ((c & 3) ^ ((rr >> 1) & 3)) * 8;
      const size_t go = (size_t)(col0 + rr) * ldb + kb + sw;
      gload16(BhT + go, &BshF[buf][c * 8]);
      gload16(BlT + go, &BslF[buf][c * 8]);
    }
  };
  auto loadA32 = [&](int kt) {
    #pragma unroll
    for (int p = 0; p < 4; ++p) {
      const int m = (tid >> 3) + p * 32;
      int row = row0 + m; row = row < M ? row : M - 1;
      areg[p] = *(const float4*)(Af + (size_t)row * ldaf + (kt << 5) + (tid & 7) * 4);
    }
  };
  auto writeA32 = [&](int buf) {
    const int q16 = (tid & 7) >> 1;
    const int sub = (tid & 1) * 4;
    #pragma unroll
    for (int p = 0; p < 4; ++p) {
      const int m = (tid >> 3) + p * 32;
      const float f[4] = {areg[p].x, areg[p].y, areg[p].z, areg[p].w};
      union { __bf16 b[4]; short4 s; } hh, ll;
      #pragma unroll
      for (int i = 0; i < 4; ++i) {
        const __bf16 hb = (__bf16)f[i];
        hh.b[i] = hb;
        ll.b[i] = (__bf16)(f[i] - (float)hb);
      }
      const int off = m * 32 + ((q16 ^ ((m >> 1) & 3)) * 8) + sub;
      *(short4*)&AshF[buf][off] = hh.s;
      *(short4*)&AslF[buf][off] = ll.s;
    }
  };

  loadA32(0);
  stageB(0, 0);
  writeA32(0);
  __syncthreads();

  int cur = 0;
  for (int kt = 0; kt < nkt; ++kt) {
    const bool more = (kt + 1 < nkt);
    if (more) { loadA32(kt + 1); stageB(cur ^ 1, kt + 1); }

    bf16x8 ah[4], al[4], bh[4], bl[4];
    #pragma unroll
    for (int t = 0; t < 4; ++t) {
      const int ar = wm * 64 + t * 16 + l15;
      const int br = wn * 64 + t * 16 + l15;
      const int as = ar * 32 + ((quad ^ ((ar >> 1) & 3)) * 8);
      const int bs = br * 32 + ((quad ^ ((br >> 1) & 3)) * 8);
      ah[t] = *(const bf16x8*)&AshF[cur][as];
      al[t] = *(const bf16x8*)&AslF[cur][as];
      bh[t] = *(const bf16x8*)&BshF[cur][bs];
      bl[t] = *(const bf16x8*)&BslF[cur][bs];
    }
    #pragma unroll
    for (int mt = 0; mt < 4; ++mt)
      #pragma unroll
      for (int nt = 0; nt < 4; ++nt) {
        acc[mt][nt] = __builtin_amdgcn_mfma_f32_16x16x32_bf16(ah[mt], bh[nt], acc[mt][nt], 0, 0, 0);
        acc[mt][nt] = __builtin_amdgcn_mfma_f32_16x16x32_bf16(ah[mt], bl[nt], acc[mt][nt], 0, 0, 0);
        acc[mt][nt] = __builtin_amdgcn_mfma_f32_16x16x32_bf16(al[mt], bh[nt], acc[mt][nt], 0, 0, 0);
      }

    if (more) writeA32(cur ^ 1);
    __syncthreads();
    cur ^= 1;
  }

  #pragma unroll
  for (int mt = 0; mt < 4; ++mt)
    #pragma unroll
    for (int nt = 0; nt < 4; ++nt) {
      const int col = col0 + wn * 64 + nt * 16 + l15;
      #pragma unroll
      for (int r = 0; r < 4; ++r) {
        const int row = row0 + wm * 64 + mt * 16 + quad * 4 + r;
        if (row < M) {
          float v = acc[mt][nt][r];
          if (leaky) v = leaky_f(v);
          if (Oh) {
            const size_t o = ((size_t)mb * kcTotO + kcOffO + (col >> 5)) * 4096
                           + (size_t)(row & 127) * 32 + (col & 31);
            const __bf16 hv = (__bf16)v;
            Oh[o] = hv;
            Ol[o] = (__bf16)(v - (float)hv);
          } else {
            C[(size_t)row * ldc + col] = v;
          }
        }
      }
    }
}

// ---------------------------------------------------------------------------
// Prep kernels
// ---------------------------------------------------------------------------
// B[z][Kd][Nd] fp32 -> tiled hi/lo [z][Nd/128][Kd/32][4096]
__global__ void splitTB_tiled(const float* __restrict__ B, __bf16* __restrict__ h,
                              __bf16* __restrict__ l, int Kd, int Nd, int total)
{
  int i = blockIdx.x * 256 + threadIdx.x;
  if (i >= total) return;
  int z   = i / (Kd * Nd);
  int rem = i - z * (Kd * Nd);
  int k = rem / Nd;
  int n = rem - k * Nd;
  float v = B[i];
  __bf16 hv = (__bf16)v;
  size_t o = ((size_t)z * (Nd / 128) * (Kd / 32) + (size_t)(n >> 7) * (Kd / 32) + (k >> 5)) * 4096
           + (size_t)(n & 127) * 32 + (k & 31);
  h[o] = hv;
  l[o] = (__bf16)(v - (float)hv);
}

// B[z][Kd][Nd] fp32 -> linear hi/lo [z][Nd][Kd] (for the AF32 kernel's B)
__global__ void splitT_linear(const float* __restrict__ B, __bf16* __restrict__ h,
                              __bf16* __restrict__ l, int Kd, int Nd, int total)
{
  int i = blockIdx.x * 256 + threadIdx.x;
  if (i >= total) return;
  int z   = i / (Kd * Nd);
  int rem = i - z * (Kd * Nd);
  int k = rem / Nd;
  int n = rem - k * Nd;
  float v = B[i];
  __bf16 hv = (__bf16)v;
  long o = (long)z * Kd * Nd + (long)n * Kd + k;
  h[o] = hv;
  l[o] = (__bf16)(v - (float)hv);
}

// x [N_NODES][512] fp32 -> tiled hi/lo [391][16][4096], pad rows zeroed
__global__ void splitX_tiled(const float* __restrict__ x, __bf16* __restrict__ h,
                             __bf16* __restrict__ l)
{
  long i = (long)blockIdx.x * 256 + threadIdx.x;
  if (i >= (long)M_PAD * IN_F) return;
  const int row = (int)(i >> 9);
  const int k   = (int)(i & 511);
  const float v = (row < N_NODES) ? x[(size_t)row * IN_F + k] : 0.0f;
  const __bf16 hv = (__bf16)v;
  const size_t o = ((size_t)(row >> 7) * 16 + (k >> 5)) * 4096 + (size_t)(row & 127) * 32 + (k & 31);
  h[o] = hv;
  l[o] = (__bf16)(v - (float)hv);
}

// Bcat tiled-B over full K=2048: output-col n rows, kidx = d*512+k.
// k<H: invW[d*H+k][n]; else 0.5*sum_b att[d*4+b]*invW[b*H+(k-H)][n]
__global__ void bcat_tiled(const float* __restrict__ invW, const float* __restrict__ att,
                           __bf16* __restrict__ h, __bf16* __restrict__ l)
{
  int i = blockIdx.x * 256 + threadIdx.x;           // over 4*512*512
  if (i >= NDIM * OUT_F * 512) return;
  int d   = i >> 18;
  int rem = i & 262143;
  int n = rem >> 9;
  int k = rem & 511;
  float v;
  if (k < H_F) {
    v = invW[(long)(d * H_F + k) * OUT_F + n];
  } else {
    float s = 0.f;
    #pragma unroll
    for (int b = 0; b < 4; ++b)
      s += att[d * 4 + b] * invW[(long)(b * H_F + (k - H_F)) * OUT_F + n];
    v = 0.5f * s;
  }
  __bf16 hv = (__bf16)v;
  const int kidx = d * 512 + k;
  const size_t o = ((size_t)(n >> 7) * 64 + (kidx >> 5)) * 4096 + (size_t)(n & 127) * 32 + (kidx & 31);
  h[o] = hv;
  l[o] = (__bf16)(v - (float)hv);
}

// ---------------------------------------------------------------------------
// CSR build
// ---------------------------------------------------------------------------
__global__ void deg_count_kernel(const int* __restrict__ edges, int* __restrict__ cnt, int E)
{
  int i = blockIdx.x * 256 + threadIdx.x;
  if (i >= NDIM * E) return;
  int d = i / E;
  int e = i - d * E;
  int t = edges[(long)d * 2 * E + E + e];
  atomicAdd(&cnt[d * N_NODES + t], 1);
}

__global__ __launch_bounds__(1024) void scan_kernel(const int* __restrict__ cnt,
                                                    int* __restrict__ row_start,
                                                    float* __restrict__ dinv)
{
  const int d    = blockIdx.x;
  const int tid  = threadIdx.x;
  const int lane = tid & 63;
  const int wid  = tid >> 6;
  __shared__ int wsum[16];
  __shared__ int carry_s;
  if (tid == 0) carry_s = 0;
  __syncthreads();
  for (int base = 0; base < N_NODES; base += 1024) {
    int i = base + tid;
    int v = (i < N_NODES) ? cnt[d * N_NODES + i] : 0;
    if (i < N_NODES) dinv[d * N_NODES + i] = sqrtf(0.5f / (float)(v + 1));
    int incl = v;
    #pragma unroll
    for (int off = 1; off < 64; off <<= 1) {
      int nb = __shfl_up(incl, off, 64);
      if (lane >= off) incl += nb;
    }
    if (lane == 63) wsum[wid] = incl;
    __syncthreads();
    if (wid == 0 && lane < 16) {
      int s = wsum[lane];
      #pragma unroll
      for (int off = 1; off < 16; off <<= 1) {
        int nb = __shfl_up(s, off, 16);
        if (lane >= off) s += nb;
      }
      wsum[lane] = s;
    }
    __syncthreads();
    int waveoff = (wid == 0) ? 0 : wsum[wid - 1];
    if (i < N_NODES) row_start[d * (N_NODES + 1) + i] = carry_s + waveoff + incl - v;
    __syncthreads();
    if (tid == 1023) carry_s += wsum[15];
    __syncthreads();
  }
  if (tid == 0) row_start[d * (N_NODES + 1) + N_NODES] = carry_s;
}

__global__ void fill_kernel(const int* __restrict__ edges, const int* __restrict__ row_start,
                            int* __restrict__ fill_cnt, int* __restrict__ csr_src, int E)
{
  int i = blockIdx.x * 256 + threadIdx.x;
  if (i >= NDIM * E) return;
  int d = i / E;
  int e = i - d * E;
  int s = edges[(long)d * 2 * E + e];
  int t = edges[(long)d * 2 * E + E + e];
  int pos = row_start[d * (N_NODES + 1) + t] + atomicAdd(&fill_cnt[d * N_NODES + t], 1);
  csr_src[(long)d * E + pos] = s;
}

// ---------------------------------------------------------------------------
// Gather: one wave per dst node, 4-edge unroll; writes WB split-bf16 into the
// TILED fat-A slot (kcOffW = dim-slot chunk base).
// ---------------------------------------------------------------------------
__global__ __launch_bounds__(256) void gather_aggr_kernel(
    const float* __restrict__ hw, const int* __restrict__ csr_src,
    const int* __restrict__ row_start, const float* __restrict__ dinv,
    const float* __restrict__ bias, __bf16* __restrict__ Wh, __bf16* __restrict__ Wl,
    int kcTotW, int kcOffW)
{
  const int n = blockIdx.x * 4 + (threadIdx.x >> 6);
  const int lane = threadIdx.x & 63;
  const float dt = dinv[n];
  const float sl = dt * dt;
  const float4 b = *(const float4*)(bias + lane * 4);
  const float4 h = *(const float4*)(hw + (size_t)n * H_F + lane * 4);
  float4 a0 = make_float4(0.5f * b.x + sl * h.x, 0.5f * b.y + sl * h.y,
                          0.5f * b.z + sl * h.z, 0.5f * b.w + sl * h.w);
  float4 a1 = make_float4(0.f, 0.f, 0.f, 0.f);
  float4 a2 = make_float4(0.f, 0.f, 0.f, 0.f);
  float4 a3 = make_float4(0.f, 0.f, 0.f, 0.f);
  const int beg = row_start[n];
  const int end = row_start[n + 1];
  int j = beg;
  for (; j + 4 <= end; j += 4) {
    const int s0 = csr_src[j];
    const int s1 = csr_src[j + 1];
    const int s2 = csr_src[j + 2];
    const int s3 = csr_src[j + 3];
    const float nm0 = dt * dinv[s0];
    const float nm1 = dt * dinv[s1];
    const float nm2 = dt * dinv[s2];
    const float nm3 = dt * dinv[s3];
    const float4 v0 = *(const float4*)(hw + (size_t)s0 * H_F + lane * 4);
    const float4 v1 = *(const float4*)(hw + (size_t)s1 * H_F + lane * 4);
    const float4 v2 = *(const float4*)(hw + (size_t)s2 * H_F + lane * 4);
    const float4 v3 = *(const float4*)(hw + (size_t)s3 * H_F + lane * 4);
    a0.x = fmaf(nm0, v0.x, a0.x); a0.y = fmaf(nm0, v0.y, a0.y);
    a0.z = fmaf(nm0, v0.z, a0.z); a0.w = fmaf(nm0, v0.w, a0.w);
    a1.x = fmaf(nm1, v1.x, a1.x); a1.y = fmaf(nm1, v1.y, a1.y);
    a1.z = fmaf(nm1, v1.z, a1.z); a1.w = fmaf(nm1, v1.w, a1.w);
    a2.x = fmaf(nm2, v2.x, a2.x); a2.y = fmaf(nm2, v2.y, a2.y);
    a2.z = fmaf(nm2, v2.z, a2.z); a2.w = fmaf(nm2, v2.w, a2.w);
    a3.x = fmaf(nm3, v3.x, a3.x); a3.y = fmaf(nm3, v3.y, a3.y);
    a3.z = fmaf(nm3, v3.z, a3.z); a3.w = fmaf(nm3, v3.w, a3.w);
  }
  for (; j < end; ++j) {
    const int s0 = csr_src[j];
    const float nm0 = dt * dinv[s0];
    const float4 v0 = *(const float4*)(hw + (size_t)s0 * H_F + lane * 4);
    a0.x = fmaf(nm0, v0.x, a0.x); a0.y = fmaf(nm0, v0.y, a0.y);
    a0.z = fmaf(nm0, v0.z, a0.z); a0.w = fmaf(nm0, v0.w, a0.w);
  }
  const float av[4] = {a0.x + a1.x + a2.x + a3.x, a0.y + a1.y + a2.y + a3.y,
                       a0.z + a1.z + a2.z + a3.z, a0.w + a1.w + a2.w + a3.w};
  union { __bf16 b[4]; short4 s; } H, L;
  #pragma unroll
  for (int i = 0; i < 4; ++i) {
    const __bf16 hv = (__bf16)av[i];
    H.b[i] = hv;
    L.b[i] = (__bf16)(av[i] - (float)hv);
  }
  // tiled write: col = lane*4 .. lane*4+3 (within one 8-elem group)
  const size_t o = ((size_t)(n >> 7) * kcTotW + kcOffW + (lane >> 3)) * 4096
                 + (size_t)(n & 127) * 32 + (lane & 7) * 4;
  *(short4*)(Wh + o) = H.s;
  *(short4*)(Wl + o) = L.s;
}

// ---------------------------------------------------------------------------
// Attention small kernels
// ---------------------------------------------------------------------------
__global__ void att_dot_kernel(const float* __restrict__ T, const float* __restrict__ P,
                               float* __restrict__ out16)
{
  const int a = blockIdx.x >> 2;
  const int b = blockIdx.x & 3;
  const float* ta = T + (long)a * (IN_F * H_F);
  const float* pb = P + (long)b * (IN_F * H_F);
  float s = 0.f;
  for (int i = threadIdx.x; i < IN_F * H_F; i += 256) s += ta[i] * pb[i];
  #pragma unroll
  for (int off = 32; off > 0; off >>= 1) s += __shfl_down(s, off, 64);
  __shared__ float red[4];
  if ((threadIdx.x & 63) == 0) red[threadIdx.x >> 6] = s;
  __syncthreads();
  if (threadIdx.x == 0) out16[blockIdx.x] = red[0] + red[1] + red[2] + red[3];
}

__global__ void att_softmax_kernel(const float* __restrict__ raw, float* __restrict__ att)
{
  int b = threadIdx.x;
  if (b < 4) {
    float r0 = raw[b], r1 = raw[4 + b], r2 = raw[8 + b], r3 = raw[12 + b];
    float m = fmaxf(fmaxf(r0, r1), fmaxf(r2, r3));
    float e0 = expf(r0 - m), e1 = expf(r1 - m), e2 = expf(r2 - m), e3 = expf(r3 - m);
    float inv = 1.0f / (e0 + e1 + e2 + e3);
    att[b] = e0 * inv; att[4 + b] = e1 * inv; att[8 + b] = e2 * inv; att[12 + b] = e3 * inv;
  }
}

// ---------------------------------------------------------------------------
extern "C" void kernel_launch(void* const* d_in, const int* in_sizes, int n_in,
                              void* d_out, int out_size, void* d_ws, size_t ws_size,
                              hipStream_t stream)
{
  const float* x     = (const float*)d_in[0];
  const int*   edges = (const int*)d_in[1];
  const float* proj  = (const float*)d_in[2];
  const float* gcnW  = (const float*)d_in[3];
  const float* gcnB  = (const float*)d_in[4];
  const float* bil   = (const float*)d_in[5];
  const float* invW  = (const float*)d_in[6];
  const float* invB  = (const float*)d_in[7];
  float* out = (float*)d_out;

  // ---- workspace: fixed part (~81 MB) ----
  float* HWB       = (float*)d_ws;                    // NH (fp32 scratch for gather)
  float* dinv      = HWB + NH;                        // NDIM*N
  float* Tbuf      = dinv + NDIM * N_NODES;           // NDIM*IN_F*H_F
  float* att_raw   = Tbuf + (long)NDIM * IN_F * H_F;  // 16
  float* att       = att_raw + 16;                    // 16
  int*   cnt       = (int*)(att + 16);                // NDIM*N
  int*   fill_cnt  = cnt + NDIM * N_NODES;            // NDIM*N
  int*   row_start = fill_cnt + NDIM * N_NODES;       // NDIM*(N+1)
  int*   csr_src   = row_start + NDIM * (N_NODES + 1);// NDIM*E
  __bf16* projLinH = (__bf16*)(csr_src + (long)NDIM * N_EDGE);   // [4][256 n][512 k]
  __bf16* projLinL = projLinH + (long)NDIM * IN_F * H_F;
  __bf16* bilLinH  = projLinL + (long)NDIM * IN_F * H_F;         // [256 n][256 k]
  __bf16* bilLinL  = bilLinH + (long)H_F * H_F;
  __bf16* projTBh  = bilLinL + (long)H_F * H_F;                  // tiled [4][2][16][4096]
  __bf16* projTBl  = projTBh + (long)NDIM * 32 * 4096;
  __bf16* gcnWTBh  = projTBl + (long)NDIM * 32 * 4096;           // tiled [4][2][8][4096]
  __bf16* gcnWTBl  = gcnWTBh + (long)NDIM * 16 * 4096;
  __bf16* bcatTBh  = gcnWTBl + (long)NDIM * 16 * 4096;           // tiled [4 nb][64 kc][4096]
  __bf16* bcatTBl  = bcatTBh + (long)4 * 64 * 4096;
  __bf16* dynBase  = bcatTBl + (long)4 * 64 * 4096;

  // ---- tiers: fat = [WB_d|R_d] per dim-slot, tiled [391][KTOT/32][4096] ----
  const size_t base_bytes = (size_t)((char*)dynBase - (char*)d_ws);
  auto fatBytes = [](int ktot) { return (size_t)2 * 391 * (ktot / 32) * 4096 * sizeof(__bf16); };
  const size_t xBytes = (size_t)2 * 391 * 16 * 4096 * sizeof(__bf16);   // 102.5 MB
  int KTOT; bool XS;
  if      (ws_size >= base_bytes + fatBytes(2048) + xBytes) { KTOT = 2048; XS = true;  }
  else if (ws_size >= base_bytes + fatBytes(1024) + xBytes) { KTOT = 1024; XS = true;  }
  else if (ws_size >= base_bytes + fatBytes(512)  + xBytes) { KTOT = 512;  XS = true;  }
  else                                                      { KTOT = 512;  XS = false; }
  const int DPG  = KTOT / 512;
  const int NGEN = NDIM / DPG;
  const int KC   = KTOT / 32;

  __bf16* fatH = dynBase;
  __bf16* fatL = fatH + (size_t)391 * KC * 4096;
  __bf16* xh   = fatL + (size_t)391 * KC * 4096;      // valid only if XS
  __bf16* xl   = xh + (size_t)391 * 16 * 4096;

  const int MBL = 391;

  // --- CSR build ---
  hipMemsetAsync(cnt, 0, (size_t)2 * NDIM * N_NODES * sizeof(int), stream);
  deg_count_kernel<<<(NDIM * N_EDGE + 255) / 256, 256, 0, stream>>>(edges, cnt, N_EDGE);
  scan_kernel<<<NDIM, 1024, 0, stream>>>(cnt, row_start, dinv);
  fill_kernel<<<(NDIM * N_EDGE + 255) / 256, 256, 0, stream>>>(edges, row_start, fill_cnt,
                                                               csr_src, N_EDGE);

  // --- weight prep ---
  splitT_linear<<<(NDIM * IN_F * H_F + 255) / 256, 256, 0, stream>>>(
      proj, projLinH, projLinL, IN_F, H_F, NDIM * IN_F * H_F);
  splitT_linear<<<(H_F * H_F + 255) / 256, 256, 0, stream>>>(
      bil, bilLinH, bilLinL, H_F, H_F, H_F * H_F);
  splitTB_tiled<<<(NDIM * IN_F * H_F + 255) / 256, 256, 0, stream>>>(
      proj, projTBh, projTBl, IN_F, H_F, NDIM * IN_F * H_F);
  splitTB_tiled<<<(NDIM * H_F * H_F + 255) / 256, 256, 0, stream>>>(
      gcnW, gcnWTBh, gcnWTBl, H_F, H_F, NDIM * H_F * H_F);

  // --- attention: T_a = proj_a @ bil (AF32 LDS kernel), dot, softmax, Bcat ---
  for (int a = 0; a < NDIM; ++a)
    gemm_af32<<<dim3(H_F / 128, IN_F / 128), 256, 0, stream>>>(
        proj + (long)a * IN_F * H_F, H_F,
        bilLinH, bilLinL, H_F,
        Tbuf + (long)a * IN_F * H_F, H_F,
        nullptr, nullptr, 0, 0,
        IN_F, H_F, 0);
  att_dot_kernel<<<16, 256, 0, stream>>>(Tbuf, proj, att_raw);
  att_softmax_kernel<<<1, 64, 0, stream>>>(att_raw, att);
  bcat_tiled<<<(NDIM * OUT_F * 512 + 255) / 256, 256, 0, stream>>>(invW, att, bcatTBh, bcatTBl);

  if (XS)
    splitX_tiled<<<(int)(((long)M_PAD * IN_F + 255) / 256), 256, 0, stream>>>(x, xh, xl);

  // --- per-generation pipeline ---
  for (int g = 0; g < NGEN; ++g) {
    for (int j = 0; j < DPG; ++j) {
      const int d   = g * DPG + j;
      const int kcW = j * 16;       // WB chunk base within fat
      const int kcR = j * 16 + 8;   // R chunk base within fat

      // G1: R_d = leaky(x @ proj[d]) -> tiled fat slot
      if (XS)
        gemm_s<<<dim3(H_F / 128, MBL), 256, 0, stream>>>(
            xh, xl, 16, 0,
            projTBh + (size_t)d * 32 * 4096, projTBl + (size_t)d * 32 * 4096, 16, 0,
            nullptr, 0, nullptr,
            fatH, fatL, KC, kcR,
            N_NODES, IN_F, 0, 1);
      else
        gemm_af32<<<dim3(H_F / 128, MBL), 256, 0, stream>>>(
            x, IN_F,
            projLinH + (long)d * IN_F * H_F, projLinL + (long)d * IN_F * H_F, IN_F,
            nullptr, 0,
            fatH, fatL, KC, kcR,
            N_NODES, IN_F, 1);

      // G2: HWB = R_d @ gcnW[d] (fp32 linear out for gather)
      gemm_s<<<dim3(H_F / 128, MBL), 256, 0, stream>>>(
          fatH, fatL, KC, kcR,
          gcnWTBh + (size_t)d * 16 * 4096, gcnWTBl + (size_t)d * 16 * 4096, 8, 0,
          HWB, H_F, nullptr,
          nullptr, nullptr, 0, 0,
          N_NODES, H_F, 0, 0);

      // WB_d = 0.5*bias + selfloop + neighbor gather -> tiled fat slot
      gather_aggr_kernel<<<N_NODES / 4, 256, 0, stream>>>(
          HWB, csr_src + (long)d * N_EDGE, row_start + d * (N_NODES + 1),
          dinv + d * N_NODES, gcnB + d * H_F, fatH, fatL, KC, kcW);
    }

    // G3_g: out (+)= fat_g @ bcat[:, gen g cols]^T   (K = KTOT)
    gemm_s<<<dim3(OUT_F / 128, MBL), 256, 0, stream>>>(
        fatH, fatL, KC, 0,
        bcatTBh, bcatTBl, 64, g * DPG * 16,
        out, OUT_F, (g == 0) ? invB : nullptr,
        nullptr, nullptr, 0, 0,
        N_NODES, KTOT, (g == 0) ? 0 : 1, (g == NGEN - 1) ? 1 : 0);
  }

  (void)in_sizes; (void)n_in; (void)out_size;
}

// Round 6
// 2446.208 us; speedup vs baseline: 1.1965x; 1.0386x over previous
//
#include <hip/hip_runtime.h>
#include <math.h>

// Problem constants (fixed by the reference setup_inputs).
constexpr int N_NODES = 50000;
constexpr int IN_F    = 512;
constexpr int H_F     = 256;
constexpr int OUT_F   = 512;
constexpr int N_EDGE  = 800000;
constexpr int NDIM    = 4;
constexpr long NH     = (long)N_NODES * H_F;   // 12,800,000

#define LEAKY_SLOPE 0.01f

__device__ __forceinline__ float leaky_f(float v) { return v > 0.0f ? v : LEAKY_SLOPE * v; }

typedef __bf16 bf16x8 __attribute__((ext_vector_type(8)));
typedef float  f32x4  __attribute__((ext_vector_type(4)));

// Bijective XCD-aware block remap (proven r3/r5): col-fastest work ids land
// contiguously on one XCD so col-blocks sharing an A row-panel share its L2.
__device__ __forceinline__ void swz_block(int& mb, int& nb) {
  const int nwg = (int)(gridDim.x * gridDim.y);
  const int hw  = (int)(blockIdx.y * gridDim.x + blockIdx.x);
  const int xcd = hw & 7, idx = hw >> 3;
  const int q8 = nwg >> 3, r8 = nwg & 7;
  const int wk = (xcd < r8 ? xcd * (q8 + 1) : r8 * (q8 + 1) + (xcd - r8) * q8) + idx;
  nb = wk % (int)gridDim.x;
  mb = wk / (int)gridDim.x;
}

// ---------------------------------------------------------------------------
// Split-bf16 MFMA GEMM, reg-staged, single LDS buffer, load-early schedule.
//   per K-step: readFrags(cur) -> issue global loads(kt+1) -> MFMA(cur)
//               -> __syncthreads -> cvt+ds_write(kt+1) -> __syncthreads
//   Loads ride in flight under the MFMA block + barrier (T14) instead of
//   being consumed immediately (round-0's exposed latency).
//   LDS: linear [128][32] bf16 per array + chunk-XOR map on ds_write/ds_read
//   (r3-verified: SQ_LDS_BANK_CONFLICT = 0). 32.8 KB -> 4 blocks/CU.
//   AF32=true : A fp32 (x / proj), float4 loads + VALU hi/lo split.
//   AF32=false: A pre-split bf16 hi/lo (fat R/WB buffer), int4 copies, no cvt.
//   3 MFMA per product (hh + hl + lh) for ~fp32 accuracy.
// Epilogue: optional bias vector, fp32 accumulate, leaky; store fp32 C or
// split-bf16 Oh/Ol (row-major, leading dim ldo).
// ---------------------------------------------------------------------------
template<bool AF32>
__global__ __launch_bounds__(256) void gemm_k(
    const float* __restrict__ Af, int ldaf,
    const __bf16* __restrict__ Ah, const __bf16* __restrict__ Al, int lda,
    const __bf16* __restrict__ BhT, const __bf16* __restrict__ BlT, int ldb,
    float* __restrict__ C, int ldc, const float* __restrict__ biasVec,
    __bf16* __restrict__ Oh, __bf16* __restrict__ Ol, int ldo,
    int M, int K, int accumulate, int leaky)
{
  __shared__ __bf16 Ash[4096];
  __shared__ __bf16 Asl[4096];
  __shared__ __bf16 Bsh[4096];
  __shared__ __bf16 Bsl[4096];

  const int tid  = threadIdx.x;
  const int lane = tid & 63;
  const int wid  = tid >> 6;
  const int wm   = wid & 1;
  const int wn   = wid >> 1;
  const int l15  = lane & 15;
  const int quad = lane >> 4;

  int mb, nb;
  swz_block(mb, nb);
  const int row0 = mb * 128;
  const int col0 = nb * 128;

  f32x4 acc[4][4] = {};
  const int nkt = K >> 5;

  // staging registers
  int4   avh0, avh1, avl0, avl1;   // !AF32 A
  int4   bvh0, bvh1, bvl0, bvl1;   // B
  float4 ar0, ar1, ar2, ar3;       // AF32 A

  const int rrB = tid >> 2;        // 0..63 (+64 second pass)
  const int qB  = tid & 3;

  auto loadB = [&](int kt) {
    const int kb = kt << 5;
    const size_t s0 = (size_t)(col0 + rrB) * ldb + kb + qB * 8;
    const size_t s1 = (size_t)(col0 + rrB + 64) * ldb + kb + qB * 8;
    bvh0 = *(const int4*)(BhT + s0);
    bvl0 = *(const int4*)(BlT + s0);
    bvh1 = *(const int4*)(BhT + s1);
    bvl1 = *(const int4*)(BlT + s1);
  };
  auto writeB = [&]() {
    const int o0 = rrB * 32 + ((qB ^ ((rrB >> 1) & 3)) << 3);
    const int r1 = rrB + 64;
    const int o1 = r1 * 32 + ((qB ^ ((r1 >> 1) & 3)) << 3);
    *(int4*)&Bsh[o0] = bvh0;
    *(int4*)&Bsl[o0] = bvl0;
    *(int4*)&Bsh[o1] = bvh1;
    *(int4*)&Bsl[o1] = bvl1;
  };
  auto loadA16 = [&](int kt) {
    const int kb = kt << 5;
    int r0c = row0 + rrB;      r0c = r0c < M ? r0c : M - 1;
    int r1c = row0 + rrB + 64; r1c = r1c < M ? r1c : M - 1;
    const size_t s0 = (size_t)r0c * lda + kb + qB * 8;
    const size_t s1 = (size_t)r1c * lda + kb + qB * 8;
    avh0 = *(const int4*)(Ah + s0);
    avl0 = *(const int4*)(Al + s0);
    avh1 = *(const int4*)(Ah + s1);
    avl1 = *(const int4*)(Al + s1);
  };
  auto writeA16 = [&]() {
    const int o0 = rrB * 32 + ((qB ^ ((rrB >> 1) & 3)) << 3);
    const int r1 = rrB + 64;
    const int o1 = r1 * 32 + ((qB ^ ((r1 >> 1) & 3)) << 3);
    *(int4*)&Ash[o0] = avh0;
    *(int4*)&Asl[o0] = avl0;
    *(int4*)&Ash[o1] = avh1;
    *(int4*)&Asl[o1] = avl1;
  };
  auto loadA32 = [&](int kt) {
    const int kb = (kt << 5) + (tid & 7) * 4;
    const int m  = tid >> 3;   // 0..31, +32 per pass
    int r;
    r = row0 + m;      r = r < M ? r : M - 1; ar0 = *(const float4*)(Af + (size_t)r * ldaf + kb);
    r = row0 + m + 32; r = r < M ? r : M - 1; ar1 = *(const float4*)(Af + (size_t)r * ldaf + kb);
    r = row0 + m + 64; r = r < M ? r : M - 1; ar2 = *(const float4*)(Af + (size_t)r * ldaf + kb);
    r = row0 + m + 96; r = r < M ? r : M - 1; ar3 = *(const float4*)(Af + (size_t)r * ldaf + kb);
  };
  auto writeA32 = [&]() {
    const int q16 = (tid & 7) >> 1;
    const int sub = (tid & 1) * 4;
    const int m0  = tid >> 3;
    const float4 regs[4] = {ar0, ar1, ar2, ar3};
    #pragma unroll
    for (int p = 0; p < 4; ++p) {
      const int m = m0 + p * 32;
      const float f[4] = {regs[p].x, regs[p].y, regs[p].z, regs[p].w};
      union { __bf16 b[4]; short4 s; } hh, ll;
      #pragma unroll
      for (int i = 0; i < 4; ++i) {
        const __bf16 hb = (__bf16)f[i];
        hh.b[i] = hb;
        ll.b[i] = (__bf16)(f[i] - (float)hb);
      }
      const int off = m * 32 + ((q16 ^ ((m >> 1) & 3)) << 3) + sub;
      *(short4*)&Ash[off] = hh.s;
      *(short4*)&Asl[off] = ll.s;
    }
  };

  // ---- prologue: tile 0 into LDS ------------------------------------------
  if constexpr (AF32) { loadA32(0); } else { loadA16(0); }
  loadB(0);
  if constexpr (AF32) { writeA32(); } else { writeA16(); }
  writeB();
  __syncthreads();

  // ---- main loop: frags+MFMA(cur) with loads(kt+1) in flight --------------
  for (int kt = 0; kt < nkt; ++kt) {
    bf16x8 fah[4], fal[4], fbh[4], fbl[4];
    #pragma unroll
    for (int t = 0; t < 4; ++t) {
      const int ar = wm * 64 + t * 16 + l15;
      const int br = wn * 64 + t * 16 + l15;
      const int as = ar * 32 + ((quad ^ ((ar >> 1) & 3)) << 3);
      const int bs = br * 32 + ((quad ^ ((br >> 1) & 3)) << 3);
      fah[t] = *(const bf16x8*)&Ash[as];
      fal[t] = *(const bf16x8*)&Asl[as];
      fbh[t] = *(const bf16x8*)&Bsh[bs];
      fbl[t] = *(const bf16x8*)&Bsl[bs];
    }

    const bool more = (kt + 1) < nkt;
    if (more) {
      if constexpr (AF32) { loadA32(kt + 1); } else { loadA16(kt + 1); }
      loadB(kt + 1);
    }

    #pragma unroll
    for (int mt = 0; mt < 4; ++mt)
      #pragma unroll
      for (int nt = 0; nt < 4; ++nt) {
        acc[mt][nt] = __builtin_amdgcn_mfma_f32_16x16x32_bf16(fah[mt], fbh[nt], acc[mt][nt], 0, 0, 0);
        acc[mt][nt] = __builtin_amdgcn_mfma_f32_16x16x32_bf16(fah[mt], fbl[nt], acc[mt][nt], 0, 0, 0);
        acc[mt][nt] = __builtin_amdgcn_mfma_f32_16x16x32_bf16(fal[mt], fbh[nt], acc[mt][nt], 0, 0, 0);
      }

    __syncthreads();            // all waves done reading; loads have landed
    if (more) {
      if constexpr (AF32) { writeA32(); } else { writeA16(); }
      writeB();
    }
    __syncthreads();            // next tile visible
  }

  // ---- epilogue: C/D layout col=lane&15, row=quad*4+reg --------------------
  #pragma unroll
  for (int mt = 0; mt < 4; ++mt)
    #pragma unroll
    for (int nt = 0; nt < 4; ++nt) {
      const int col = col0 + wn * 64 + nt * 16 + l15;
      const float bv = biasVec ? biasVec[col] : 0.0f;
      #pragma unroll
      for (int r = 0; r < 4; ++r) {
        const int row = row0 + wm * 64 + mt * 16 + quad * 4 + r;
        if (row < M) {
          float v = acc[mt][nt][r] + bv;
          if (accumulate) v += C[(size_t)row * ldc + col];
          if (leaky) v = leaky_f(v);
          if (Oh) {
            const __bf16 hv = (__bf16)v;
            Oh[(size_t)row * ldo + col] = hv;
            Ol[(size_t)row * ldo + col] = (__bf16)(v - (float)hv);
          } else {
            C[(size_t)row * ldc + col] = v;
          }
        }
      }
    }
}

// ---------------------------------------------------------------------------
// Weight prep: transpose + hi/lo split.  B:[Z][Kd][Nd] -> out:[Z][Nd][Kd]
// ---------------------------------------------------------------------------
__global__ void splitT_kernel(const float* __restrict__ B, __bf16* __restrict__ h,
                              __bf16* __restrict__ l, int Kd, int Nd, int total)
{
  int i = blockIdx.x * 256 + threadIdx.x;
  if (i >= total) return;
  int z   = i / (Kd * Nd);
  int rem = i - z * (Kd * Nd);
  int k = rem / Nd;
  int n = rem - k * Nd;
  float v = B[i];
  __bf16 hv = (__bf16)v;
  long o = (long)z * Kd * Nd + (long)n * Kd + k;
  h[o] = hv;
  l[o] = (__bf16)(v - (float)hv);
}

// Bcat stacked: out layout [n][2048], kidx = d*512 + k.
// k<H: invW[d*H+k][n]; else 0.5*sum_b att[d*4+b]*invW[b*H+(k-H)][n]
__global__ void bcat_kernel(const float* __restrict__ invW, const float* __restrict__ att,
                            __bf16* __restrict__ h, __bf16* __restrict__ l)
{
  int i = blockIdx.x * 256 + threadIdx.x;           // over 4*512*512
  if (i >= NDIM * OUT_F * 512) return;
  int d   = i >> 18;
  int rem = i & 262143;
  int n = rem >> 9;
  int k = rem & 511;
  float v;
  if (k < H_F) {
    v = invW[(long)(d * H_F + k) * OUT_F + n];
  } else {
    float s = 0.f;
    #pragma unroll
    for (int b = 0; b < 4; ++b)
      s += att[d * 4 + b] * invW[(long)(b * H_F + (k - H_F)) * OUT_F + n];
    v = 0.5f * s;
  }
  __bf16 hv = (__bf16)v;
  long o = (long)n * (NDIM * 512) + d * 512 + k;
  h[o] = hv;
  l[o] = (__bf16)(v - (float)hv);
}

// ---------------------------------------------------------------------------
// CSR build
// ---------------------------------------------------------------------------
__global__ void deg_count_kernel(const int* __restrict__ edges, int* __restrict__ cnt, int E)
{
  int i = blockIdx.x * 256 + threadIdx.x;
  if (i >= NDIM * E) return;
  int d = i / E;
  int e = i - d * E;
  int t = edges[(long)d * 2 * E + E + e];
  atomicAdd(&cnt[d * N_NODES + t], 1);
}

__global__ __launch_bounds__(1024) void scan_kernel(const int* __restrict__ cnt,
                                                    int* __restrict__ row_start,
                                                    float* __restrict__ dinv)
{
  const int d    = blockIdx.x;
  const int tid  = threadIdx.x;
  const int lane = tid & 63;
  const int wid  = tid >> 6;
  __shared__ int wsum[16];
  __shared__ int carry_s;
  if (tid == 0) carry_s = 0;
  __syncthreads();
  for (int base = 0; base < N_NODES; base += 1024) {
    int i = base + tid;
    int v = (i < N_NODES) ? cnt[d * N_NODES + i] : 0;
    if (i < N_NODES) dinv[d * N_NODES + i] = sqrtf(0.5f / (float)(v + 1));
    int incl = v;
    #pragma unroll
    for (int off = 1; off < 64; off <<= 1) {
      int nb = __shfl_up(incl, off, 64);
      if (lane >= off) incl += nb;
    }
    if (lane == 63) wsum[wid] = incl;
    __syncthreads();
    if (wid == 0 && lane < 16) {
      int s = wsum[lane];
      #pragma unroll
      for (int off = 1; off < 16; off <<= 1) {
        int nb = __shfl_up(s, off, 16);
        if (lane >= off) s += nb;
      }
      wsum[lane] = s;
    }
    __syncthreads();
    int waveoff = (wid == 0) ? 0 : wsum[wid - 1];
    if (i < N_NODES) row_start[d * (N_NODES + 1) + i] = carry_s + waveoff + incl - v;
    __syncthreads();
    if (tid == 1023) carry_s += wsum[15];
    __syncthreads();
  }
  if (tid == 0) row_start[d * (N_NODES + 1) + N_NODES] = carry_s;
}

__global__ void fill_kernel(const int* __restrict__ edges, const int* __restrict__ row_start,
                            int* __restrict__ fill_cnt, int* __restrict__ csr_src, int E)
{
  int i = blockIdx.x * 256 + threadIdx.x;
  if (i >= NDIM * E) return;
  int d = i / E;
  int e = i - d * E;
  int s = edges[(long)d * 2 * E + e];
  int t = edges[(long)d * 2 * E + E + e];
  int pos = row_start[d * (N_NODES + 1) + t] + atomicAdd(&fill_cnt[d * N_NODES + t], 1);
  csr_src[(long)d * E + pos] = s;
}

// ---------------------------------------------------------------------------
// Gather: one wave per dst node, 4-edge unroll (r5-proven); writes WB split
// bf16 into the fat slot (row-major, leading dim ldw).
// ---------------------------------------------------------------------------
__global__ __launch_bounds__(256) void gather_aggr_kernel(
    const float* __restrict__ hw, const int* __restrict__ csr_src,
    const int* __restrict__ row_start, const float* __restrict__ dinv,
    const float* __restrict__ bias, __bf16* __restrict__ Wh, __bf16* __restrict__ Wl,
    int ldw)
{
  const int n = blockIdx.x * 4 + (threadIdx.x >> 6);
  const int lane = threadIdx.x & 63;
  const float dt = dinv[n];
  const float sl = dt * dt;
  const float4 b = *(const float4*)(bias + lane * 4);
  const float4 h = *(const float4*)(hw + (size_t)n * H_F + lane * 4);
  float4 a0 = make_float4(0.5f * b.x + sl * h.x, 0.5f * b.y + sl * h.y,
                          0.5f * b.z + sl * h.z, 0.5f * b.w + sl * h.w);
  float4 a1 = make_float4(0.f, 0.f, 0.f, 0.f);
  float4 a2 = make_float4(0.f, 0.f, 0.f, 0.f);
  float4 a3 = make_float4(0.f, 0.f, 0.f, 0.f);
  const int beg = row_start[n];
  const int end = row_start[n + 1];
  int j = beg;
  for (; j + 4 <= end; j += 4) {
    const int s0 = csr_src[j];
    const int s1 = csr_src[j + 1];
    const int s2 = csr_src[j + 2];
    const int s3 = csr_src[j + 3];
    const float nm0 = dt * dinv[s0];
    const float nm1 = dt * dinv[s1];
    const float nm2 = dt * dinv[s2];
    const float nm3 = dt * dinv[s3];
    const float4 v0 = *(const float4*)(hw + (size_t)s0 * H_F + lane * 4);
    const float4 v1 = *(const float4*)(hw + (size_t)s1 * H_F + lane * 4);
    const float4 v2 = *(const float4*)(hw + (size_t)s2 * H_F + lane * 4);
    const float4 v3 = *(const float4*)(hw + (size_t)s3 * H_F + lane * 4);
    a0.x = fmaf(nm0, v0.x, a0.x); a0.y = fmaf(nm0, v0.y, a0.y);
    a0.z = fmaf(nm0, v0.z, a0.z); a0.w = fmaf(nm0, v0.w, a0.w);
    a1.x = fmaf(nm1, v1.x, a1.x); a1.y = fmaf(nm1, v1.y, a1.y);
    a1.z = fmaf(nm1, v1.z, a1.z); a1.w = fmaf(nm1, v1.w, a1.w);
    a2.x = fmaf(nm2, v2.x, a2.x); a2.y = fmaf(nm2, v2.y, a2.y);
    a2.z = fmaf(nm2, v2.z, a2.z); a2.w = fmaf(nm2, v2.w, a2.w);
    a3.x = fmaf(nm3, v3.x, a3.x); a3.y = fmaf(nm3, v3.y, a3.y);
    a3.z = fmaf(nm3, v3.z, a3.z); a3.w = fmaf(nm3, v3.w, a3.w);
  }
  for (; j < end; ++j) {
    const int s0 = csr_src[j];
    const float nm0 = dt * dinv[s0];
    const float4 v0 = *(const float4*)(hw + (size_t)s0 * H_F + lane * 4);
    a0.x = fmaf(nm0, v0.x, a0.x); a0.y = fmaf(nm0, v0.y, a0.y);
    a0.z = fmaf(nm0, v0.z, a0.z); a0.w = fmaf(nm0, v0.w, a0.w);
  }
  const float av[4] = {a0.x + a1.x + a2.x + a3.x, a0.y + a1.y + a2.y + a3.y,
                       a0.z + a1.z + a2.z + a3.z, a0.w + a1.w + a2.w + a3.w};
  union { __bf16 b[4]; short4 s; } H, L;
  #pragma unroll
  for (int i = 0; i < 4; ++i) {
    const __bf16 hv = (__bf16)av[i];
    H.b[i] = hv;
    L.b[i] = (__bf16)(av[i] - (float)hv);
  }
  *(short4*)(Wh + (size_t)n * ldw + lane * 4) = H.s;
  *(short4*)(Wl + (size_t)n * ldw + lane * 4) = L.s;
}

// ---------------------------------------------------------------------------
// Attention small kernels
// ---------------------------------------------------------------------------
__global__ void att_dot_kernel(const float* __restrict__ T, const float* __restrict__ P,
                               float* __restrict__ out16)
{
  const int a = blockIdx.x >> 2;
  const int b = blockIdx.x & 3;
  const float* ta = T + (long)a * (IN_F * H_F);
  const float* pb = P + (long)b * (IN_F * H_F);
  float s = 0.f;
  for (int i = threadIdx.x; i < IN_F * H_F; i += 256) s += ta[i] * pb[i];
  #pragma unroll
  for (int off = 32; off > 0; off >>= 1) s += __shfl_down(s, off, 64);
  __shared__ float red[4];
  if ((threadIdx.x & 63) == 0) red[threadIdx.x >> 6] = s;
  __syncthreads();
  if (threadIdx.x == 0) out16[blockIdx.x] = red[0] + red[1] + red[2] + red[3];
}

__global__ void att_softmax_kernel(const float* __restrict__ raw, float* __restrict__ att)
{
  int b = threadIdx.x;
  if (b < 4) {
    float r0 = raw[b], r1 = raw[4 + b], r2 = raw[8 + b], r3 = raw[12 + b];
    float m = fmaxf(fmaxf(r0, r1), fmaxf(r2, r3));
    float e0 = expf(r0 - m), e1 = expf(r1 - m), e2 = expf(r2 - m), e3 = expf(r3 - m);
    float inv = 1.0f / (e0 + e1 + e2 + e3);
    att[b] = e0 * inv; att[4 + b] = e1 * inv; att[8 + b] = e2 * inv; att[12 + b] = e3 * inv;
  }
}

// ---------------------------------------------------------------------------
extern "C" void kernel_launch(void* const* d_in, const int* in_sizes, int n_in,
                              void* d_out, int out_size, void* d_ws, size_t ws_size,
                              hipStream_t stream)
{
  const float* x     = (const float*)d_in[0];
  const int*   edges = (const int*)d_in[1];
  const float* proj  = (const float*)d_in[2];
  const float* gcnW  = (const float*)d_in[3];
  const float* gcnB  = (const float*)d_in[4];
  const float* bil   = (const float*)d_in[5];
  const float* invW  = (const float*)d_in[6];
  const float* invB  = (const float*)d_in[7];
  float* out = (float*)d_out;

  // ---- workspace: fixed part (~77 MB) ----
  float* HWB       = (float*)d_ws;                    // NH fp32 (gather input)
  float* dinv      = HWB + NH;                        // NDIM*N
  float* Tbuf      = dinv + NDIM * N_NODES;           // NDIM*IN_F*H_F
  float* att_raw   = Tbuf + (long)NDIM * IN_F * H_F;  // 16
  float* att       = att_raw + 16;                    // 16
  int*   cnt       = (int*)(att + 16);                // NDIM*N
  int*   fill_cnt  = cnt + NDIM * N_NODES;            // NDIM*N
  int*   row_start = fill_cnt + NDIM * N_NODES;       // NDIM*(N+1)
  int*   csr_src   = row_start + NDIM * (N_NODES + 1);// NDIM*E
  __bf16* projTh   = (__bf16*)(csr_src + (long)NDIM * N_EDGE);   // [4][256n][512k]
  __bf16* projTl   = projTh + (long)NDIM * IN_F * H_F;
  __bf16* gcnWTh   = projTl + (long)NDIM * IN_F * H_F;           // [4][256n][256k]
  __bf16* gcnWTl   = gcnWTh + (long)NDIM * H_F * H_F;
  __bf16* bcatTh   = gcnWTl + (long)NDIM * H_F * H_F;            // [512n][2048k]
  __bf16* bcatTl   = bcatTh + (long)NDIM * OUT_F * 512;
  __bf16* bilTh    = bcatTl + (long)NDIM * OUT_F * 512;          // [256n][256k]
  __bf16* bilTl    = bilTh + (long)H_F * H_F;
  __bf16* fatH     = bilTl + (long)H_F * H_F;

  // ---- merge tiers: fat = [WB_j|R_j]*DPG rows [N_NODES][KTOT] hi/lo ----
  const size_t base_bytes = (size_t)((char*)fatH - (char*)d_ws);
  auto fatBytes = [](int ktot) { return (size_t)2 * N_NODES * ktot * sizeof(__bf16); };
  int KTOT;
  if      (ws_size >= base_bytes + fatBytes(2048)) KTOT = 2048;
  else if (ws_size >= base_bytes + fatBytes(1024)) KTOT = 1024;
  else                                             KTOT = 512;
  const int DPG  = KTOT / 512;
  const int NGEN = NDIM / DPG;
  __bf16* fatL = fatH + (size_t)N_NODES * KTOT;

  const int MBL = (N_NODES + 127) / 128;              // 391

  // --- CSR build ---
  hipMemsetAsync(cnt, 0, (size_t)2 * NDIM * N_NODES * sizeof(int), stream);
  deg_count_kernel<<<(NDIM * N_EDGE + 255) / 256, 256, 0, stream>>>(edges, cnt, N_EDGE);
  scan_kernel<<<NDIM, 1024, 0, stream>>>(cnt, row_start, dinv);
  fill_kernel<<<(NDIM * N_EDGE + 255) / 256, 256, 0, stream>>>(edges, row_start, fill_cnt,
                                                               csr_src, N_EDGE);

  // --- weight prep (transpose + split) ---
  splitT_kernel<<<(NDIM * IN_F * H_F + 255) / 256, 256, 0, stream>>>(
      proj, projTh, projTl, IN_F, H_F, NDIM * IN_F * H_F);
  splitT_kernel<<<(NDIM * H_F * H_F + 255) / 256, 256, 0, stream>>>(
      gcnW, gcnWTh, gcnWTl, H_F, H_F, NDIM * H_F * H_F);
  splitT_kernel<<<(H_F * H_F + 255) / 256, 256, 0, stream>>>(
      bil, bilTh, bilTl, H_F, H_F, H_F * H_F);

  // --- attention: T_a = proj_a @ bil (AF32), dot, softmax, Bcat ---
  for (int a = 0; a < NDIM; ++a)
    gemm_k<true><<<dim3(H_F / 128, IN_F / 128), 256, 0, stream>>>(
        proj + (long)a * IN_F * H_F, H_F,
        nullptr, nullptr, 0,
        bilTh, bilTl, H_F,
        Tbuf + (long)a * IN_F * H_F, H_F, nullptr,
        nullptr, nullptr, 0,
        IN_F, H_F, 0, 0);
  att_dot_kernel<<<16, 256, 0, stream>>>(Tbuf, proj, att_raw);
  att_softmax_kernel<<<1, 64, 0, stream>>>(att_raw, att);
  bcat_kernel<<<(NDIM * OUT_F * 512 + 255) / 256, 256, 0, stream>>>(invW, att, bcatTh, bcatTl);

  // --- per-generation pipeline ---
  for (int g = 0; g < NGEN; ++g) {
    for (int j = 0; j < DPG; ++j) {
      const int d = g * DPG + j;
      __bf16* wbH = fatH + j * 512;          // WB_d: fat cols j*512 .. +255
      __bf16* wbL = fatL + j * 512;
      __bf16* rH  = fatH + j * 512 + 256;    // R_d : fat cols j*512+256 .. +511
      __bf16* rL  = fatL + j * 512 + 256;

      // G1: R_d = leaky(x @ proj[d]) -> split bf16 fat slot  (AF32 A)
      gemm_k<true><<<dim3(H_F / 128, MBL), 256, 0, stream>>>(
          x, IN_F,
          nullptr, nullptr, 0,
          projTh + (long)d * IN_F * H_F, projTl + (long)d * IN_F * H_F, IN_F,
          nullptr, 0, nullptr,
          rH, rL, KTOT,
          N_NODES, IN_F, 0, 1);

      // G2: HWB = R_d @ gcnW[d] (fp32 out for gather)  (pre-split A)
      gemm_k<false><<<dim3(H_F / 128, MBL), 256, 0, stream>>>(
          nullptr, 0,
          rH, rL, KTOT,
          gcnWTh + (long)d * H_F * H_F, gcnWTl + (long)d * H_F * H_F, H_F,
          HWB, H_F, nullptr,
          nullptr, nullptr, 0,
          N_NODES, H_F, 0, 0);

      // WB_d = 0.5*bias + selfloop + neighbor gather -> split bf16 fat slot
      gather_aggr_kernel<<<N_NODES / 4, 256, 0, stream>>>(
          HWB, csr_src + (long)d * N_EDGE, row_start + d * (N_NODES + 1),
          dinv + d * N_NODES, gcnB + d * H_F, wbH, wbL, KTOT);
    }

    // G3_g: out (+)= fat @ bcat[:, g*KTOT..]^T   (K=KTOT; g0 folds invB)
    gemm_k<false><<<dim3(OUT_F / 128, MBL), 256, 0, stream>>>(
        nullptr, 0,
        fatH, fatL, KTOT,
        bcatTh + (long)g * KTOT, bcatTl + (long)g * KTOT, NDIM * 512,
        out, OUT_F, (g == 0) ? invB : nullptr,
        nullptr, nullptr, 0,
        N_NODES, KTOT, (g == 0) ? 0 : 1, (g == NGEN - 1) ? 1 : 0);
  }

  (void)in_sizes; (void)n_in; (void)out_size;
}